// Round 12
// baseline (224.067 us; speedup 1.0000x reference)
//
#include <hip/hip_runtime.h>
#include <hip/hip_bf16.h>

#define RESV 32
#define R3V (RESV * RESV * RESV)
#define R3P1 (R3V + 1)
#define CH 64  // sorted points per wave-chunk in k_gather4 (R6-proven)

__device__ __forceinline__ unsigned short f2bf(float f) {
    __hip_bfloat16 h = __float2bfloat16(f);  // RNE
    unsigned short u;
    __builtin_memcpy(&u, &h, 2);
    return u;
}
__device__ __forceinline__ unsigned int pkbf(float lo, float hi) {
    return (unsigned int)f2bf(lo) | ((unsigned int)f2bf(hi) << 16);
}
__device__ __forceinline__ float blo(unsigned int u) { return __uint_as_float(u << 16); }
__device__ __forceinline__ float bhi(unsigned int u) { return __uint_as_float(u & 0xffff0000u); }

// ws header (floats): [0, 768) per-batch sum partials part[b*96 + x*3 + d]
//                     [768, 1024) per-batch max partials maxp[b*32 + x]

// ---- K1: per-batch per-block coordinate sums -> partials (no atomics) ----
// Also zeroes counts (stream-ordered before k_points; distinct buffer;
// 256 blocks x 256 threads x int4 == B*R3V ints for B=8).
__global__ void k_sums(const float* __restrict__ coords, float* __restrict__ part,
                       int4* __restrict__ counts4, int N) {
    const int b = blockIdx.y;
    {
        const int g = (blockIdx.y * gridDim.x + blockIdx.x) * blockDim.x + threadIdx.x;
        counts4[g] = make_int4(0, 0, 0, 0);
    }
    const float* cb = coords + (size_t)b * 3 * N;
    float sx = 0.f, sy = 0.f, sz = 0.f;
    for (int n = blockIdx.x * blockDim.x + threadIdx.x; n < N; n += gridDim.x * blockDim.x) {
        sx += cb[n];
        sy += cb[N + n];
        sz += cb[2 * N + n];
    }
    for (int off = 32; off > 0; off >>= 1) {
        sx += __shfl_down(sx, off);
        sy += __shfl_down(sy, off);
        sz += __shfl_down(sz, off);
    }
    __shared__ float red[3][4];
    const int lane = threadIdx.x & 63;
    const int wv   = threadIdx.x >> 6;
    if (lane == 0) { red[0][wv] = sx; red[1][wv] = sy; red[2][wv] = sz; }
    __syncthreads();
    if (threadIdx.x == 0) {
        float tx = 0.f, ty = 0.f, tz = 0.f;
        const int nw = blockDim.x >> 6;
        for (int w = 0; w < nw; ++w) { tx += red[0][w]; ty += red[1][w]; tz += red[2][w]; }
        float* p = part + (b * 32 + blockIdx.x) * 3;
        p[0] = tx; p[1] = ty; p[2] = tz;
    }
}

// ---- K2: per-batch per-block max radius -> partials (no atomics) ----
__global__ void k_maxrad(const float* __restrict__ coords, const float* __restrict__ part,
                         float* __restrict__ maxp, int N) {
    const int b = blockIdx.y;
    __shared__ float sp[96];
    if (threadIdx.x < 96) sp[threadIdx.x] = part[b * 96 + threadIdx.x];
    __syncthreads();
    const float invN = 1.0f / (float)N;
    float mx = 0.f, my = 0.f, mz = 0.f;
    for (int x = 0; x < 32; ++x) { mx += sp[x * 3]; my += sp[x * 3 + 1]; mz += sp[x * 3 + 2]; }
    mx *= invN; my *= invN; mz *= invN;

    const float* cb = coords + (size_t)b * 3 * N;
    float r = 0.f;
    for (int n = blockIdx.x * blockDim.x + threadIdx.x; n < N; n += gridDim.x * blockDim.x) {
        const float dx = cb[n] - mx;
        const float dy = cb[N + n] - my;
        const float dz = cb[2 * N + n] - mz;
        r = fmaxf(r, sqrtf(dx * dx + dy * dy + dz * dz));
    }
    for (int off = 32; off > 0; off >>= 1) r = fmaxf(r, __shfl_down(r, off));
    __shared__ float red[4];
    const int lane = threadIdx.x & 63;
    const int wv   = threadIdx.x >> 6;
    if (lane == 0) red[wv] = r;
    __syncthreads();
    if (threadIdx.x == 0) {
        const int nw = blockDim.x >> 6;
        float t = 0.f;
        for (int w = 0; w < nw; ++w) t = fmaxf(t, red[w]);
        maxp[b * 32 + blockIdx.x] = t;
    }
}

// ---- K3: norm coords + packed (voxel idx << 17 | rank); counts via atomic return ----
__global__ void k_points(const float* __restrict__ coords, const float* __restrict__ part,
                         const float* __restrict__ maxp,
                         float* __restrict__ norm_out, unsigned int* __restrict__ pk,
                         int* __restrict__ counts, int N) {
    const int b = blockIdx.y;
    __shared__ float sp[96];
    __shared__ float mp[32];
    if (threadIdx.x < 96) sp[threadIdx.x] = part[b * 96 + threadIdx.x];
    if (threadIdx.x < 32) mp[threadIdx.x] = maxp[b * 32 + threadIdx.x];
    __syncthreads();
    const float invN = 1.0f / (float)N;
    float mean[3] = {0.f, 0.f, 0.f};
    float mrad = 0.f;
    for (int x = 0; x < 32; ++x) {
        mean[0] += sp[x * 3]; mean[1] += sp[x * 3 + 1]; mean[2] += sp[x * 3 + 2];
        mrad = fmaxf(mrad, mp[x]);
    }
    const float scale = 2.0f * mrad;

    const int n = blockIdx.x * blockDim.x + threadIdx.x;
    if (n >= N) return;
    const float* cb = coords + (size_t)b * 3 * N;
    float* nb = norm_out + (size_t)b * 3 * N;

    int flat = 0;
#pragma unroll
    for (int d = 0; d < 3; ++d) {
        float nc = (cb[d * N + n] - mean[d] * invN) / scale + 0.5f;
        nc = fminf(fmaxf(nc * (float)RESV, 0.0f), (float)(RESV - 1));
        nb[d * N + n] = nc;
        flat = flat * RESV + (int)rintf(nc);
    }
    const int jl = atomicAdd(&counts[b * R3V + flat], 1);
    pk[(size_t)b * N + n] = ((unsigned int)flat << 17) | (unsigned int)jl;
}

// ---- K4: per-batch exclusive scan of counts -> start (stride R3P1, sentinel) ----
__global__ __launch_bounds__(1024, 1) void k_scan(const int* __restrict__ counts,
                                                  int* __restrict__ start, int N) {
    const int b = blockIdx.x;
    const int t = threadIdx.x;
    const int base  = b * R3V + t * 32;
    const int baseS = b * R3P1 + t * 32;
    int c[32];
    int T = 0;
#pragma unroll
    for (int i = 0; i < 32; ++i) { c[i] = counts[base + i]; T += c[i]; }
    int incl = T;
    const int lane = t & 63;
    for (int off = 1; off < 64; off <<= 1) {
        int y = __shfl_up(incl, off);
        if (lane >= off) incl += y;
    }
    __shared__ int wsum[16];
    __shared__ int wbase[16];
    const int w = t >> 6;
    if (lane == 63) wsum[w] = incl;
    __syncthreads();
    if (t == 0) {
        int run = 0;
        for (int i = 0; i < 16; ++i) { wbase[i] = run; run += wsum[i]; }
    }
    __syncthreads();
    int run = wbase[w] + incl - T;  // exclusive prefix
#pragma unroll
    for (int i = 0; i < 32; ++i) {
        start[baseS + i] = run;
        run += c[i];
    }
    if (t == 1023) start[b * R3P1 + R3V] = run;  // == N
}

// ---- K5: feats [B,64,N] fp32 -> fTs [B,N,64] bf16, rows in sorted order ----
// 2D grid (x = n-tile, y = batch). Store phase: dwordx2 per lane (4 channels),
// 16 lanes = one 128B row, 4 rows per wave instruction, 4 passes (was 8).
__global__ __launch_bounds__(1024, 2) void k_transpose_perm(
        const float* __restrict__ feats, const unsigned int* __restrict__ pk,
        const int* __restrict__ startv,
        unsigned int* __restrict__ fTs32, int* __restrict__ voxid, int N) {
    __shared__ unsigned short tile[256][66];
    __shared__ int jrow[256];
    const int b  = blockIdx.y;
    const int n0 = blockIdx.x * 256;
    const int t  = threadIdx.x;
    const float* fb = feats + (size_t)b * 64 * N;

    const int c = t >> 4;
    const int q = t & 15;
    if (n0 + 256 <= N) {
#pragma unroll
        for (int i = 0; i < 4; ++i) {
            const int nn = q * 4 + i * 64;
            const float4 f = *(const float4*)(fb + (size_t)c * N + n0 + nn);
            tile[nn + 0][c] = f2bf(f.x);
            tile[nn + 1][c] = f2bf(f.y);
            tile[nn + 2][c] = f2bf(f.z);
            tile[nn + 3][c] = f2bf(f.w);
        }
    } else {
        for (int i = 0; i < 4; ++i) {
            const int nn = q * 4 + i * 64;
            for (int u = 0; u < 4; ++u) {
                const int n = n0 + nn + u;
                tile[nn + u][c] = f2bf((n < N) ? fb[(size_t)c * N + n] : 0.f);
            }
        }
    }
    if (t < 256) {
        const int n = n0 + t;
        if (n < N) {
            const unsigned int p = pk[(size_t)b * N + n];
            const int v = (int)(p >> 17);
            const int j = startv[(size_t)b * R3P1 + v] + (int)(p & 0x1FFFFu);
            jrow[t] = j;
            voxid[(size_t)b * N + j] = v;
        }
    }
    __syncthreads();

    // ---- permuted store: 4 passes, 4 rows per wave instruction, 8B/lane ----
    const int wv   = t >> 6;        // wave 0..15
    const int lane = t & 63;
    const int lc   = lane & 15;     // channel quad (channels 4lc..4lc+3)
    const int pr   = lane >> 4;     // row index within the 4-row group
    uint2* fo2 = (uint2*)fTs32 + (size_t)b * N * 16;  // row stride 16 uint2
#pragma unroll
    for (int k = 0; k < 4; ++k) {
        const int p = k * 64 + wv * 4 + pr;  // 0..255
        if (n0 + p < N) {
            const uint2 d = *(const uint2*)&tile[p][4 * lc];
            fo2[(size_t)jrow[p] * 16 + lc] = d;
        }
    }
}

// ---- K6: atomic-free segmented reduction over sorted rows (2D grid) ----
__global__ __launch_bounds__(256) void k_gather4(const unsigned int* __restrict__ fTs32,
                                                 const int* __restrict__ voxid,
                                                 const int* __restrict__ startv,
                                                 unsigned int* __restrict__ gridT2,
                                                 int N, int nchunk) {
    const int w     = threadIdx.x >> 6;
    const int lane  = threadIdx.x & 63;
    const int p     = lane >> 4;   // row parity 0..3
    const int lc    = lane & 15;   // channel quad
    const int chunk = blockIdx.x * 4 + w;
    if (chunk >= nchunk) return;
    const int b    = blockIdx.y;
    const int c0   = chunk * CH;
    const int end0 = min(c0 + CH, N);
    const uint2* fb = (const uint2*)(fTs32 + (size_t)b * N * 32);
    const int* vi = voxid  + (size_t)b * N;
    const int* sv = startv + (size_t)b * R3P1;
    uint2* gT = (uint2*)(gridT2) + (size_t)b * R3V * 16;

    int j;
    {
        const int v = vi[c0];
        const int s = sv[v];
        j = (s < c0) ? sv[v + 1] : s;
    }
    while (j < end0) {
        const int v = vi[j];           // wave-uniform
        const int e = sv[v + 1];
        float a0 = 0.f, a1 = 0.f, a2 = 0.f, a3 = 0.f;
        int r = j + p;
        for (; r + 12 < e; r += 16) {  // 4 uint2 loads in flight per lane
            const uint2 u0 = fb[(size_t)(r + 0) * 16 + lc];
            const uint2 u1 = fb[(size_t)(r + 4) * 16 + lc];
            const uint2 u2 = fb[(size_t)(r + 8) * 16 + lc];
            const uint2 u3 = fb[(size_t)(r + 12) * 16 + lc];
            a0 += (blo(u0.x) + blo(u1.x)) + (blo(u2.x) + blo(u3.x));
            a1 += (bhi(u0.x) + bhi(u1.x)) + (bhi(u2.x) + bhi(u3.x));
            a2 += (blo(u0.y) + blo(u1.y)) + (blo(u2.y) + blo(u3.y));
            a3 += (bhi(u0.y) + bhi(u1.y)) + (bhi(u2.y) + bhi(u3.y));
        }
        for (; r < e; r += 4) {
            const uint2 u = fb[(size_t)r * 16 + lc];
            a0 += blo(u.x);
            a1 += bhi(u.x);
            a2 += blo(u.y);
            a3 += bhi(u.y);
        }
        a0 += __shfl_xor(a0, 16); a0 += __shfl_xor(a0, 32);
        a1 += __shfl_xor(a1, 16); a1 += __shfl_xor(a1, 32);
        a2 += __shfl_xor(a2, 16); a2 += __shfl_xor(a2, 32);
        a3 += __shfl_xor(a3, 16); a3 += __shfl_xor(a3, 32);
        if (p == 0) {
            gT[(size_t)v * 16 + lc] = make_uint2(pkbf(a0, a1), pkbf(a2, a3));
        }
        j = e;
    }
}

// ---- K7: gridT bf16 [B,R3,64] -> grid fp32 [B,64,R3], /cnt, cnt==0 -> 0 ----
__global__ __launch_bounds__(256) void k_fin(const unsigned int* __restrict__ gridT2,
                                             const int* __restrict__ counts,
                                             float* __restrict__ grid) {
    __shared__ float tile[64][65];
    const int b    = blockIdx.y;
    const int v0   = blockIdx.x * 64;
    const int t    = threadIdx.x;
    const int lane = t & 63;
    const int w    = t >> 6;
    const unsigned int* g = gridT2 + ((size_t)b * R3V + v0) * 32;
#pragma unroll
    for (int k = 0; k < 8; ++k) {
        const int i  = t + k * 256;  // v*32 + cd
        const int v  = i >> 5;
        const int cd = i & 31;
        const unsigned int u = g[i];
        tile[v][2 * cd]     = blo(u);
        tile[v][2 * cd + 1] = bhi(u);
    }
    __syncthreads();
    const int cnt  = counts[(size_t)b * R3V + v0 + lane];
    const float rc = 1.0f / fmaxf((float)cnt, 1.0f);
    const bool occ = cnt > 0;
    float* gb = grid + (size_t)b * 64 * R3V;
#pragma unroll
    for (int k = 0; k < 16; ++k) {
        const int c = w + k * 4;
        gb[(size_t)c * R3V + v0 + lane] = occ ? tile[lane][c] * rc : 0.0f;
    }
}

// ============================ fallback: LDS-atomic scatter ============================

__device__ __forceinline__ int swz(int v) {
    return v ^ ((v >> 5) & 31) ^ ((v >> 10) & 31);
}

__global__ void k_recip_fb(const int* __restrict__ cnt, float* __restrict__ recip, int total) {
    const int i = blockIdx.x * blockDim.x + threadIdx.x;
    if (i < total) recip[i] = 1.0f / fmaxf((float)cnt[i], 1.0f);
}

__global__ __launch_bounds__(1024, 1) void k_scatter_lds(
        const float* __restrict__ feats, const unsigned int* __restrict__ pk,
        const float* __restrict__ recip, float* __restrict__ grid, int N, int C) {
    extern __shared__ float acc[];
    const int bc  = blockIdx.x;
    const int b   = bc / C;
    const int tid = threadIdx.x;
    for (int i = tid * 4; i < R3V; i += blockDim.x * 4)
        *(float4*)(acc + i) = make_float4(0.f, 0.f, 0.f, 0.f);
    __syncthreads();
    const float* fb = feats + (size_t)bc * N;
    const unsigned int* ib = pk + (size_t)b * N;
    for (int n = tid; n < N; n += blockDim.x) atomicAdd(&acc[swz((int)(ib[n] >> 17))], fb[n]);
    __syncthreads();
    const float* rb = recip + (size_t)b * R3V;
    float*       gb = grid  + (size_t)bc * R3V;
    for (int i = tid; i < R3V; i += blockDim.x)
        gb[i] = acc[swz(i)] * rb[i];
}

// ============================ launch ============================

extern "C" void kernel_launch(void* const* d_in, const int* in_sizes, int n_in,
                              void* d_out, int out_size, void* d_ws, size_t ws_size,
                              hipStream_t stream) {
    const float* feats  = (const float*)d_in[0];
    const float* coords = (const float*)d_in[1];

    const long long s0 = in_sizes[0], s1 = in_sizes[1];
    const int BC = (int)(((long long)out_size - s1) / R3V);  // B*C
    const int N  = (int)(s0 / BC);
    const int B  = (int)(s1 / (3LL * N));
    const int C  = BC / B;

    float* out_grid = (float*)d_out;               // [B, C, R3]
    float* out_norm = out_grid + (size_t)BC * R3V; // [B, 3, N]

    // ws layout (float32 slots). Header = 1024 floats (sum + max partials).
    const size_t BR3 = (size_t)B * R3V;
    const size_t BN  = (size_t)B * N;
    const size_t o_counts = 1024;
    const size_t o_start  = o_counts + BR3;
    const size_t o_recip  = o_start + (size_t)B * R3P1;  // fallback only
    const size_t o_pk     = o_recip + BR3;
    const size_t o_voxid  = o_pk + BN;
    size_t o_gridT = (o_voxid + BN + 63) & ~(size_t)63;        // bf16: BR3*32 slots
    size_t o_fTs   = (o_gridT + BR3 * 32 + 63) & ~(size_t)63;  // bf16: BN*32 slots
    const size_t need = (o_fTs + BN * 32) * sizeof(float);

    float*        ws_part = (float*)d_ws;                  // [B*32*3]
    float*        ws_maxp = (float*)d_ws + 768;            // [B*32]
    int*          counts  = (int*)d_ws + o_counts;
    int*          startv  = (int*)d_ws + o_start;
    float*        recip   = (float*)d_ws + o_recip;
    unsigned int* pk      = (unsigned int*)d_ws + o_pk;
    int*          voxid   = (int*)d_ws + o_voxid;
    unsigned int* gridT2  = (unsigned int*)((float*)d_ws + o_gridT);
    unsigned int* fTs32   = (unsigned int*)((float*)d_ws + o_fTs);

    const int BLK = 256;
    dim3 gRed(32, B);
    // k_sums also zeroes counts (B*R3V ints == 256 blocks * 256 threads * int4)
    k_sums<<<gRed, BLK, 0, stream>>>(coords, ws_part, (int4*)counts, N);
    k_maxrad<<<gRed, BLK, 0, stream>>>(coords, ws_part, ws_maxp, N);

    dim3 gPts((N + BLK - 1) / BLK, B);
    k_points<<<gPts, BLK, 0, stream>>>(coords, ws_part, ws_maxp, out_norm, pk, counts, N);

    if (ws_size >= need && C == 64) {
        k_scan<<<dim3(B), 1024, 0, stream>>>(counts, startv, N);
        dim3 gT((N + 255) / 256, B);
        k_transpose_perm<<<gT, 1024, 0, stream>>>(feats, pk, startv, fTs32, voxid, N);
        const int nchunk = (N + CH - 1) / CH;
        dim3 gG((nchunk + 3) / 4, B);
        k_gather4<<<gG, 256, 0, stream>>>(fTs32, voxid, startv, gridT2, N, nchunk);
        dim3 gF(R3V / 64, B);
        k_fin<<<gF, 256, 0, stream>>>(gridT2, counts, out_grid);
    } else {
        const int tot = B * R3V;
        k_recip_fb<<<(tot + BLK - 1) / BLK, BLK, 0, stream>>>(counts, recip, tot);
        k_scatter_lds<<<dim3(BC), 1024, R3V * sizeof(float), stream>>>(
            feats, pk, recip, out_grid, N, C);
    }
}

// Round 14
// 213.978 us; speedup vs baseline: 1.0472x; 1.0472x over previous
//
#include <hip/hip_runtime.h>
#include <hip/hip_bf16.h>

#define RESV 32
#define R3V (RESV * RESV * RESV)
#define R3P1 (R3V + 1)
#define CH 64    // sorted points per wave-chunk in k_gather4 (R6-proven)
#define PB 128   // partial-reduction blocks per batch (occupancy: 4 blocks/CU)

__device__ __forceinline__ unsigned short f2bf(float f) {
    __hip_bfloat16 h = __float2bfloat16(f);  // RNE
    unsigned short u;
    __builtin_memcpy(&u, &h, 2);
    return u;
}
__device__ __forceinline__ unsigned int pkbf(float lo, float hi) {
    return (unsigned int)f2bf(lo) | ((unsigned int)f2bf(hi) << 16);
}
__device__ __forceinline__ float blo(unsigned int u) { return __uint_as_float(u << 16); }
__device__ __forceinline__ float bhi(unsigned int u) { return __uint_as_float(u & 0xffff0000u); }

// ws header (floats): [0, 3072) per-batch sum partials part[b*PB*3 + x*3 + d] (PB=128)
//                     [3072, 4096) per-batch max partials maxp[b*PB + x]

// ---- K1: per-batch per-block coordinate sums -> partials (no atomics, float4) ----
// Also zeroes counts (stream-ordered before k_points; distinct buffer).
__global__ void k_sums(const float* __restrict__ coords, float* __restrict__ part,
                       int4* __restrict__ counts4, int nInt4, int N) {
    const int b = blockIdx.y;
    {
        const int g = (blockIdx.y * gridDim.x + blockIdx.x) * blockDim.x + threadIdx.x;
        if (g < nInt4) counts4[g] = make_int4(0, 0, 0, 0);
    }
    const float* cb = coords + (size_t)b * 3 * N;
    const int N4 = N >> 2;
    float sx = 0.f, sy = 0.f, sz = 0.f;
    for (int i = blockIdx.x * blockDim.x + threadIdx.x; i < N4; i += gridDim.x * blockDim.x) {
        const float4 x = ((const float4*)cb)[i];
        const float4 y = ((const float4*)(cb + N))[i];
        const float4 z = ((const float4*)(cb + 2 * N))[i];
        sx += (x.x + x.y) + (x.z + x.w);
        sy += (y.x + y.y) + (y.z + y.w);
        sz += (z.x + z.y) + (z.z + z.w);
    }
    // tail (N not multiple of 4)
    for (int n = 4 * N4 + blockIdx.x * blockDim.x + threadIdx.x; n < N;
         n += gridDim.x * blockDim.x) {
        sx += cb[n];
        sy += cb[N + n];
        sz += cb[2 * N + n];
    }
    for (int off = 32; off > 0; off >>= 1) {
        sx += __shfl_down(sx, off);
        sy += __shfl_down(sy, off);
        sz += __shfl_down(sz, off);
    }
    __shared__ float red[3][4];
    const int lane = threadIdx.x & 63;
    const int wv   = threadIdx.x >> 6;
    if (lane == 0) { red[0][wv] = sx; red[1][wv] = sy; red[2][wv] = sz; }
    __syncthreads();
    if (threadIdx.x == 0) {
        float tx = 0.f, ty = 0.f, tz = 0.f;
        const int nw = blockDim.x >> 6;
        for (int w = 0; w < nw; ++w) { tx += red[0][w]; ty += red[1][w]; tz += red[2][w]; }
        float* p = part + (b * PB + blockIdx.x) * 3;
        p[0] = tx; p[1] = ty; p[2] = tz;
    }
}

// ---- K2: per-batch per-block max radius -> partials (no atomics, float4) ----
__global__ void k_maxrad(const float* __restrict__ coords, const float* __restrict__ part,
                         float* __restrict__ maxp, int N) {
    const int b = blockIdx.y;
    __shared__ float sp[PB * 3];
    // FIX vs R12: strided load (PB*3 = 384 > blockDim = 256; the guarded
    // single-load left sp[256..383] as garbage).
    for (int x = threadIdx.x; x < PB * 3; x += blockDim.x) sp[x] = part[b * PB * 3 + x];
    __syncthreads();
    const float invN = 1.0f / (float)N;
    float mx = 0.f, my = 0.f, mz = 0.f;
    for (int x = 0; x < PB; ++x) { mx += sp[x * 3]; my += sp[x * 3 + 1]; mz += sp[x * 3 + 2]; }
    mx *= invN; my *= invN; mz *= invN;

    const float* cb = coords + (size_t)b * 3 * N;
    const int N4 = N >> 2;
    float r = 0.f;
    for (int i = blockIdx.x * blockDim.x + threadIdx.x; i < N4; i += gridDim.x * blockDim.x) {
        const float4 x = ((const float4*)cb)[i];
        const float4 y = ((const float4*)(cb + N))[i];
        const float4 z = ((const float4*)(cb + 2 * N))[i];
        const float dx0 = x.x - mx, dy0 = y.x - my, dz0 = z.x - mz;
        const float dx1 = x.y - mx, dy1 = y.y - my, dz1 = z.y - mz;
        const float dx2 = x.z - mx, dy2 = y.z - my, dz2 = z.z - mz;
        const float dx3 = x.w - mx, dy3 = y.w - my, dz3 = z.w - mz;
        const float r0 = dx0 * dx0 + dy0 * dy0 + dz0 * dz0;
        const float r1 = dx1 * dx1 + dy1 * dy1 + dz1 * dz1;
        const float r2 = dx2 * dx2 + dy2 * dy2 + dz2 * dz2;
        const float r3 = dx3 * dx3 + dy3 * dy3 + dz3 * dz3;
        r = fmaxf(r, fmaxf(fmaxf(r0, r1), fmaxf(r2, r3)));
    }
    for (int n = 4 * N4 + blockIdx.x * blockDim.x + threadIdx.x; n < N;
         n += gridDim.x * blockDim.x) {
        const float dx = cb[n] - mx;
        const float dy = cb[N + n] - my;
        const float dz = cb[2 * N + n] - mz;
        r = fmaxf(r, dx * dx + dy * dy + dz * dz);
    }
    for (int off = 32; off > 0; off >>= 1) r = fmaxf(r, __shfl_down(r, off));
    __shared__ float red[4];
    const int lane = threadIdx.x & 63;
    const int wv   = threadIdx.x >> 6;
    if (lane == 0) red[wv] = r;
    __syncthreads();
    if (threadIdx.x == 0) {
        const int nw = blockDim.x >> 6;
        float t = 0.f;
        for (int w = 0; w < nw; ++w) t = fmaxf(t, red[w]);
        maxp[b * PB + blockIdx.x] = sqrtf(t);  // sqrt monotone: sqrt(max r^2) == max radius
    }
}

// ---- K3: norm coords + packed (voxel idx << 17 | rank); 4 points/thread ----
__global__ void k_points(const float* __restrict__ coords, const float* __restrict__ part,
                         const float* __restrict__ maxp,
                         float* __restrict__ norm_out, unsigned int* __restrict__ pk,
                         int* __restrict__ counts, int N) {
    const int b = blockIdx.y;
    __shared__ float sp[PB * 3];
    __shared__ float mp[PB];
    // FIX vs R12: strided loads (see k_maxrad).
    for (int x = threadIdx.x; x < PB * 3; x += blockDim.x) sp[x] = part[b * PB * 3 + x];
    for (int x = threadIdx.x; x < PB; x += blockDim.x) mp[x] = maxp[b * PB + x];
    __syncthreads();
    const float invN = 1.0f / (float)N;
    float mean[3] = {0.f, 0.f, 0.f};
    float mrad = 0.f;
    for (int x = 0; x < PB; ++x) {
        mean[0] += sp[x * 3]; mean[1] += sp[x * 3 + 1]; mean[2] += sp[x * 3 + 2];
        mrad = fmaxf(mrad, mp[x]);
    }
    const float scale = 2.0f * mrad;
    const float m0 = mean[0] * invN, m1 = mean[1] * invN, m2 = mean[2] * invN;

    const int i = blockIdx.x * blockDim.x + threadIdx.x;  // float4 index
    const int n0 = i * 4;
    if (n0 >= N) return;
    const float* cb = coords + (size_t)b * 3 * N;
    float* nb = norm_out + (size_t)b * 3 * N;
    int* cnts = counts + b * R3V;

    if (n0 + 4 <= N) {
        float4 cx = ((const float4*)cb)[i];
        float4 cy = ((const float4*)(cb + N))[i];
        float4 cz = ((const float4*)(cb + 2 * N))[i];
        float nx[4] = {cx.x, cx.y, cx.z, cx.w};
        float ny[4] = {cy.x, cy.y, cy.z, cy.w};
        float nz[4] = {cz.x, cz.y, cz.z, cz.w};
        int flat[4];
#pragma unroll
        for (int k = 0; k < 4; ++k) {
            float a = fminf(fmaxf(((nx[k] - m0) / scale + 0.5f) * (float)RESV, 0.0f), (float)(RESV - 1));
            float bq = fminf(fmaxf(((ny[k] - m1) / scale + 0.5f) * (float)RESV, 0.0f), (float)(RESV - 1));
            float c = fminf(fmaxf(((nz[k] - m2) / scale + 0.5f) * (float)RESV, 0.0f), (float)(RESV - 1));
            nx[k] = a; ny[k] = bq; nz[k] = c;
            flat[k] = ((int)rintf(a) * RESV + (int)rintf(bq)) * RESV + (int)rintf(c);
        }
        ((float4*)(nb))[i]         = make_float4(nx[0], nx[1], nx[2], nx[3]);
        ((float4*)(nb + N))[i]     = make_float4(ny[0], ny[1], ny[2], ny[3]);
        ((float4*)(nb + 2 * N))[i] = make_float4(nz[0], nz[1], nz[2], nz[3]);
        uint4 o;
        o.x = ((unsigned int)flat[0] << 17) | (unsigned int)atomicAdd(&cnts[flat[0]], 1);
        o.y = ((unsigned int)flat[1] << 17) | (unsigned int)atomicAdd(&cnts[flat[1]], 1);
        o.z = ((unsigned int)flat[2] << 17) | (unsigned int)atomicAdd(&cnts[flat[2]], 1);
        o.w = ((unsigned int)flat[3] << 17) | (unsigned int)atomicAdd(&cnts[flat[3]], 1);
        ((uint4*)(pk + (size_t)b * N))[i] = o;
    } else {
        for (int n = n0; n < N; ++n) {
            int flat = 0;
            float v[3] = {cb[n], cb[N + n], cb[2 * N + n]};
            float m[3] = {m0, m1, m2};
#pragma unroll
            for (int d = 0; d < 3; ++d) {
                float nc = fminf(fmaxf(((v[d] - m[d]) / scale + 0.5f) * (float)RESV, 0.0f),
                                 (float)(RESV - 1));
                nb[d * N + n] = nc;
                flat = flat * RESV + (int)rintf(nc);
            }
            const int jl = atomicAdd(&cnts[flat], 1);
            pk[(size_t)b * N + n] = ((unsigned int)flat << 17) | (unsigned int)jl;
        }
    }
}

// ---- K4: per-batch exclusive scan of counts -> start (stride R3P1, sentinel) ----
__global__ __launch_bounds__(1024, 1) void k_scan(const int* __restrict__ counts,
                                                  int* __restrict__ start, int N) {
    const int b = blockIdx.x;
    const int t = threadIdx.x;
    const int base  = b * R3V + t * 32;
    const int baseS = b * R3P1 + t * 32;
    int c[32];
    int T = 0;
#pragma unroll
    for (int i = 0; i < 32; ++i) { c[i] = counts[base + i]; T += c[i]; }
    int incl = T;
    const int lane = t & 63;
    for (int off = 1; off < 64; off <<= 1) {
        int y = __shfl_up(incl, off);
        if (lane >= off) incl += y;
    }
    __shared__ int wsum[16];
    __shared__ int wbase[16];
    const int w = t >> 6;
    if (lane == 63) wsum[w] = incl;
    __syncthreads();
    if (t == 0) {
        int run = 0;
        for (int i = 0; i < 16; ++i) { wbase[i] = run; run += wsum[i]; }
    }
    __syncthreads();
    int run = wbase[w] + incl - T;  // exclusive prefix
#pragma unroll
    for (int i = 0; i < 32; ++i) {
        start[baseS + i] = run;
        run += c[i];
    }
    if (t == 1023) start[b * R3P1 + R3V] = run;  // == N
}

// ---- K5: feats [B,64,N] fp32 -> fTs [B,N,64] bf16, rows in sorted order ----
__global__ __launch_bounds__(1024, 2) void k_transpose_perm(
        const float* __restrict__ feats, const unsigned int* __restrict__ pk,
        const int* __restrict__ startv,
        unsigned int* __restrict__ fTs32, int* __restrict__ voxid, int N) {
    __shared__ unsigned short tile[256][66];
    __shared__ int jrow[256];
    const int b  = blockIdx.y;
    const int n0 = blockIdx.x * 256;
    const int t  = threadIdx.x;
    const float* fb = feats + (size_t)b * 64 * N;

    const int c = t >> 4;
    const int q = t & 15;
    if (n0 + 256 <= N) {
#pragma unroll
        for (int i = 0; i < 4; ++i) {
            const int nn = q * 4 + i * 64;
            const float4 f = *(const float4*)(fb + (size_t)c * N + n0 + nn);
            tile[nn + 0][c] = f2bf(f.x);
            tile[nn + 1][c] = f2bf(f.y);
            tile[nn + 2][c] = f2bf(f.z);
            tile[nn + 3][c] = f2bf(f.w);
        }
    } else {
        for (int i = 0; i < 4; ++i) {
            const int nn = q * 4 + i * 64;
            for (int u = 0; u < 4; ++u) {
                const int n = n0 + nn + u;
                tile[nn + u][c] = f2bf((n < N) ? fb[(size_t)c * N + n] : 0.f);
            }
        }
    }
    if (t < 256) {
        const int n = n0 + t;
        if (n < N) {
            const unsigned int p = pk[(size_t)b * N + n];
            const int v = (int)(p >> 17);
            const int j = startv[(size_t)b * R3P1 + v] + (int)(p & 0x1FFFFu);
            jrow[t] = j;
            voxid[(size_t)b * N + j] = v;
        }
    }
    __syncthreads();

    // permuted store: 4 passes, 4 rows per wave instruction, 8B/lane
    const int wv   = t >> 6;
    const int lane = t & 63;
    const int lc   = lane & 15;     // channel quad
    const int pr   = lane >> 4;     // row within 4-row group
    uint2* fo2 = (uint2*)fTs32 + (size_t)b * N * 16;
#pragma unroll
    for (int k = 0; k < 4; ++k) {
        const int p = k * 64 + wv * 4 + pr;
        if (n0 + p < N) {
            const uint2 d = *(const uint2*)&tile[p][4 * lc];
            fo2[(size_t)jrow[p] * 16 + lc] = d;
        }
    }
}

// ---- K6: atomic-free segmented reduction over sorted rows (2D grid) ----
__global__ __launch_bounds__(256) void k_gather4(const unsigned int* __restrict__ fTs32,
                                                 const int* __restrict__ voxid,
                                                 const int* __restrict__ startv,
                                                 unsigned int* __restrict__ gridT2,
                                                 int N, int nchunk) {
    const int w     = threadIdx.x >> 6;
    const int lane  = threadIdx.x & 63;
    const int p     = lane >> 4;   // row parity 0..3
    const int lc    = lane & 15;   // channel quad
    const int chunk = blockIdx.x * 4 + w;
    if (chunk >= nchunk) return;
    const int b    = blockIdx.y;
    const int c0   = chunk * CH;
    const int end0 = min(c0 + CH, N);
    const uint2* fb = (const uint2*)(fTs32 + (size_t)b * N * 32);
    const int* vi = voxid  + (size_t)b * N;
    const int* sv = startv + (size_t)b * R3P1;
    uint2* gT = (uint2*)(gridT2) + (size_t)b * R3V * 16;

    int j;
    {
        const int v = vi[c0];
        const int s = sv[v];
        j = (s < c0) ? sv[v + 1] : s;
    }
    while (j < end0) {
        const int v = vi[j];           // wave-uniform
        const int e = sv[v + 1];
        float a0 = 0.f, a1 = 0.f, a2 = 0.f, a3 = 0.f;
        int r = j + p;
        for (; r + 12 < e; r += 16) {  // 4 uint2 loads in flight per lane
            const uint2 u0 = fb[(size_t)(r + 0) * 16 + lc];
            const uint2 u1 = fb[(size_t)(r + 4) * 16 + lc];
            const uint2 u2 = fb[(size_t)(r + 8) * 16 + lc];
            const uint2 u3 = fb[(size_t)(r + 12) * 16 + lc];
            a0 += (blo(u0.x) + blo(u1.x)) + (blo(u2.x) + blo(u3.x));
            a1 += (bhi(u0.x) + bhi(u1.x)) + (bhi(u2.x) + bhi(u3.x));
            a2 += (blo(u0.y) + blo(u1.y)) + (blo(u2.y) + blo(u3.y));
            a3 += (bhi(u0.y) + bhi(u1.y)) + (bhi(u2.y) + bhi(u3.y));
        }
        for (; r < e; r += 4) {
            const uint2 u = fb[(size_t)r * 16 + lc];
            a0 += blo(u.x);
            a1 += bhi(u.x);
            a2 += blo(u.y);
            a3 += bhi(u.y);
        }
        a0 += __shfl_xor(a0, 16); a0 += __shfl_xor(a0, 32);
        a1 += __shfl_xor(a1, 16); a1 += __shfl_xor(a1, 32);
        a2 += __shfl_xor(a2, 16); a2 += __shfl_xor(a2, 32);
        a3 += __shfl_xor(a3, 16); a3 += __shfl_xor(a3, 32);
        if (p == 0) {
            gT[(size_t)v * 16 + lc] = make_uint2(pkbf(a0, a1), pkbf(a2, a3));
        }
        j = e;
    }
}

// ---- K7: gridT bf16 [B,R3,64] -> grid fp32 [B,64,R3], /cnt, cnt==0 -> 0 ----
__global__ __launch_bounds__(256) void k_fin(const unsigned int* __restrict__ gridT2,
                                             const int* __restrict__ counts,
                                             float* __restrict__ grid) {
    __shared__ float tile[64][65];
    const int b    = blockIdx.y;
    const int v0   = blockIdx.x * 64;
    const int t    = threadIdx.x;
    const int lane = t & 63;
    const int w    = t >> 6;
    const unsigned int* g = gridT2 + ((size_t)b * R3V + v0) * 32;
#pragma unroll
    for (int k = 0; k < 8; ++k) {
        const int i  = t + k * 256;  // v*32 + cd
        const int v  = i >> 5;
        const int cd = i & 31;
        const unsigned int u = g[i];
        tile[v][2 * cd]     = blo(u);
        tile[v][2 * cd + 1] = bhi(u);
    }
    __syncthreads();
    const int cnt  = counts[(size_t)b * R3V + v0 + lane];
    const float rc = 1.0f / fmaxf((float)cnt, 1.0f);
    const bool occ = cnt > 0;
    float* gb = grid + (size_t)b * 64 * R3V;
#pragma unroll
    for (int k = 0; k < 16; ++k) {
        const int c = w + k * 4;
        gb[(size_t)c * R3V + v0 + lane] = occ ? tile[lane][c] * rc : 0.0f;
    }
}

// ============================ fallback: LDS-atomic scatter ============================

__device__ __forceinline__ int swz(int v) {
    return v ^ ((v >> 5) & 31) ^ ((v >> 10) & 31);
}

__global__ void k_recip_fb(const int* __restrict__ cnt, float* __restrict__ recip, int total) {
    const int i = blockIdx.x * blockDim.x + threadIdx.x;
    if (i < total) recip[i] = 1.0f / fmaxf((float)cnt[i], 1.0f);
}

__global__ __launch_bounds__(1024, 1) void k_scatter_lds(
        const float* __restrict__ feats, const unsigned int* __restrict__ pk,
        const float* __restrict__ recip, float* __restrict__ grid, int N, int C) {
    extern __shared__ float acc[];
    const int bc  = blockIdx.x;
    const int b   = bc / C;
    const int tid = threadIdx.x;
    for (int i = tid * 4; i < R3V; i += blockDim.x * 4)
        *(float4*)(acc + i) = make_float4(0.f, 0.f, 0.f, 0.f);
    __syncthreads();
    const float* fb = feats + (size_t)bc * N;
    const unsigned int* ib = pk + (size_t)b * N;
    for (int n = tid; n < N; n += blockDim.x) atomicAdd(&acc[swz((int)(ib[n] >> 17))], fb[n]);
    __syncthreads();
    const float* rb = recip + (size_t)b * R3V;
    float*       gb = grid  + (size_t)bc * R3V;
    for (int i = tid; i < R3V; i += blockDim.x)
        gb[i] = acc[swz(i)] * rb[i];
}

// ============================ launch ============================

extern "C" void kernel_launch(void* const* d_in, const int* in_sizes, int n_in,
                              void* d_out, int out_size, void* d_ws, size_t ws_size,
                              hipStream_t stream) {
    const float* feats  = (const float*)d_in[0];
    const float* coords = (const float*)d_in[1];

    const long long s0 = in_sizes[0], s1 = in_sizes[1];
    const int BC = (int)(((long long)out_size - s1) / R3V);  // B*C
    const int N  = (int)(s0 / BC);
    const int B  = (int)(s1 / (3LL * N));
    const int C  = BC / B;

    float* out_grid = (float*)d_out;               // [B, C, R3]
    float* out_norm = out_grid + (size_t)BC * R3V; // [B, 3, N]

    // ws layout (float32 slots). Header = 4096 floats (PB=128 partials).
    const size_t BR3 = (size_t)B * R3V;
    const size_t BN  = (size_t)B * N;
    const size_t o_counts = 4096;
    const size_t o_start  = o_counts + BR3;
    const size_t o_recip  = o_start + (size_t)B * R3P1;  // fallback only
    const size_t o_pk     = o_recip + BR3;
    const size_t o_voxid  = o_pk + BN;
    size_t o_gridT = (o_voxid + BN + 63) & ~(size_t)63;        // bf16: BR3*32 slots
    size_t o_fTs   = (o_gridT + BR3 * 32 + 63) & ~(size_t)63;  // bf16: BN*32 slots
    const size_t need = (o_fTs + BN * 32) * sizeof(float);

    float*        ws_part = (float*)d_ws;                  // [B*PB*3]
    float*        ws_maxp = (float*)d_ws + 3072;           // [B*PB]
    int*          counts  = (int*)d_ws + o_counts;
    int*          startv  = (int*)d_ws + o_start;
    float*        recip   = (float*)d_ws + o_recip;
    unsigned int* pk      = (unsigned int*)d_ws + o_pk;
    int*          voxid   = (int*)d_ws + o_voxid;
    unsigned int* gridT2  = (unsigned int*)((float*)d_ws + o_gridT);
    unsigned int* fTs32   = (unsigned int*)((float*)d_ws + o_fTs);

    const int BLK = 256;
    const int nInt4 = (int)(BR3 / 4);
    dim3 gRed(PB, B);
    // k_sums also zeroes counts (guarded; PB*B*256 threads >= BR3/4)
    k_sums<<<gRed, BLK, 0, stream>>>(coords, ws_part, (int4*)counts, nInt4, N);
    k_maxrad<<<gRed, BLK, 0, stream>>>(coords, ws_part, ws_maxp, N);

    const int nQuads = (N + 3) / 4;
    dim3 gPts((nQuads + BLK - 1) / BLK, B);
    k_points<<<gPts, BLK, 0, stream>>>(coords, ws_part, ws_maxp, out_norm, pk, counts, N);

    if (ws_size >= need && C == 64) {
        k_scan<<<dim3(B), 1024, 0, stream>>>(counts, startv, N);
        dim3 gT((N + 255) / 256, B);
        k_transpose_perm<<<gT, 1024, 0, stream>>>(feats, pk, startv, fTs32, voxid, N);
        const int nchunk = (N + CH - 1) / CH;
        dim3 gG((nchunk + 3) / 4, B);
        k_gather4<<<gG, 256, 0, stream>>>(fTs32, voxid, startv, gridT2, N, nchunk);
        dim3 gF(R3V / 64, B);
        k_fin<<<gF, 256, 0, stream>>>(gridT2, counts, out_grid);
    } else {
        const int tot = B * R3V;
        k_recip_fb<<<(tot + BLK - 1) / BLK, BLK, 0, stream>>>(counts, recip, tot);
        k_scatter_lds<<<dim3(BC), 1024, R3V * sizeof(float), stream>>>(
            feats, pk, recip, out_grid, N, C);
    }
}

// Round 15
// 195.858 us; speedup vs baseline: 1.1440x; 1.0925x over previous
//
#include <hip/hip_runtime.h>
#include <hip/hip_bf16.h>

#define RESV 32
#define R3V (RESV * RESV * RESV)
#define R3P1 (R3V + 1)
#define CH 32    // sorted points per wave-chunk in k_gather4 (R15 experiment; R14=64)
#define PB 128   // partial-reduction blocks per batch (occupancy: 4 blocks/CU)

__device__ __forceinline__ unsigned short f2bf(float f) {
    __hip_bfloat16 h = __float2bfloat16(f);  // RNE
    unsigned short u;
    __builtin_memcpy(&u, &h, 2);
    return u;
}
__device__ __forceinline__ unsigned int pkbf(float lo, float hi) {
    return (unsigned int)f2bf(lo) | ((unsigned int)f2bf(hi) << 16);
}
__device__ __forceinline__ float blo(unsigned int u) { return __uint_as_float(u << 16); }
__device__ __forceinline__ float bhi(unsigned int u) { return __uint_as_float(u & 0xffff0000u); }

// ws header (floats): [0, 3072) per-batch sum partials part[b*PB*3 + x*3 + d] (PB=128)
//                     [3072, 4096) per-batch max partials maxp[b*PB + x]

// ---- K1: per-batch per-block coordinate sums -> partials (no atomics, float4) ----
// Also zeroes counts (stream-ordered before k_points; distinct buffer).
__global__ void k_sums(const float* __restrict__ coords, float* __restrict__ part,
                       int4* __restrict__ counts4, int nInt4, int N) {
    const int b = blockIdx.y;
    {
        const int g = (blockIdx.y * gridDim.x + blockIdx.x) * blockDim.x + threadIdx.x;
        if (g < nInt4) counts4[g] = make_int4(0, 0, 0, 0);
    }
    const float* cb = coords + (size_t)b * 3 * N;
    const int N4 = N >> 2;
    float sx = 0.f, sy = 0.f, sz = 0.f;
    for (int i = blockIdx.x * blockDim.x + threadIdx.x; i < N4; i += gridDim.x * blockDim.x) {
        const float4 x = ((const float4*)cb)[i];
        const float4 y = ((const float4*)(cb + N))[i];
        const float4 z = ((const float4*)(cb + 2 * N))[i];
        sx += (x.x + x.y) + (x.z + x.w);
        sy += (y.x + y.y) + (y.z + y.w);
        sz += (z.x + z.y) + (z.z + z.w);
    }
    for (int n = 4 * N4 + blockIdx.x * blockDim.x + threadIdx.x; n < N;
         n += gridDim.x * blockDim.x) {
        sx += cb[n];
        sy += cb[N + n];
        sz += cb[2 * N + n];
    }
    for (int off = 32; off > 0; off >>= 1) {
        sx += __shfl_down(sx, off);
        sy += __shfl_down(sy, off);
        sz += __shfl_down(sz, off);
    }
    __shared__ float red[3][4];
    const int lane = threadIdx.x & 63;
    const int wv   = threadIdx.x >> 6;
    if (lane == 0) { red[0][wv] = sx; red[1][wv] = sy; red[2][wv] = sz; }
    __syncthreads();
    if (threadIdx.x == 0) {
        float tx = 0.f, ty = 0.f, tz = 0.f;
        const int nw = blockDim.x >> 6;
        for (int w = 0; w < nw; ++w) { tx += red[0][w]; ty += red[1][w]; tz += red[2][w]; }
        float* p = part + (b * PB + blockIdx.x) * 3;
        p[0] = tx; p[1] = ty; p[2] = tz;
    }
}

// ---- K2: per-batch per-block max radius -> partials (no atomics, float4) ----
__global__ void k_maxrad(const float* __restrict__ coords, const float* __restrict__ part,
                         float* __restrict__ maxp, int N) {
    const int b = blockIdx.y;
    __shared__ float sp[PB * 3];
    for (int x = threadIdx.x; x < PB * 3; x += blockDim.x) sp[x] = part[b * PB * 3 + x];
    __syncthreads();
    const float invN = 1.0f / (float)N;
    float mx = 0.f, my = 0.f, mz = 0.f;
    for (int x = 0; x < PB; ++x) { mx += sp[x * 3]; my += sp[x * 3 + 1]; mz += sp[x * 3 + 2]; }
    mx *= invN; my *= invN; mz *= invN;

    const float* cb = coords + (size_t)b * 3 * N;
    const int N4 = N >> 2;
    float r = 0.f;
    for (int i = blockIdx.x * blockDim.x + threadIdx.x; i < N4; i += gridDim.x * blockDim.x) {
        const float4 x = ((const float4*)cb)[i];
        const float4 y = ((const float4*)(cb + N))[i];
        const float4 z = ((const float4*)(cb + 2 * N))[i];
        const float dx0 = x.x - mx, dy0 = y.x - my, dz0 = z.x - mz;
        const float dx1 = x.y - mx, dy1 = y.y - my, dz1 = z.y - mz;
        const float dx2 = x.z - mx, dy2 = y.z - my, dz2 = z.z - mz;
        const float dx3 = x.w - mx, dy3 = y.w - my, dz3 = z.w - mz;
        const float r0 = dx0 * dx0 + dy0 * dy0 + dz0 * dz0;
        const float r1 = dx1 * dx1 + dy1 * dy1 + dz1 * dz1;
        const float r2 = dx2 * dx2 + dy2 * dy2 + dz2 * dz2;
        const float r3 = dx3 * dx3 + dy3 * dy3 + dz3 * dz3;
        r = fmaxf(r, fmaxf(fmaxf(r0, r1), fmaxf(r2, r3)));
    }
    for (int n = 4 * N4 + blockIdx.x * blockDim.x + threadIdx.x; n < N;
         n += gridDim.x * blockDim.x) {
        const float dx = cb[n] - mx;
        const float dy = cb[N + n] - my;
        const float dz = cb[2 * N + n] - mz;
        r = fmaxf(r, dx * dx + dy * dy + dz * dz);
    }
    for (int off = 32; off > 0; off >>= 1) r = fmaxf(r, __shfl_down(r, off));
    __shared__ float red[4];
    const int lane = threadIdx.x & 63;
    const int wv   = threadIdx.x >> 6;
    if (lane == 0) red[wv] = r;
    __syncthreads();
    if (threadIdx.x == 0) {
        const int nw = blockDim.x >> 6;
        float t = 0.f;
        for (int w = 0; w < nw; ++w) t = fmaxf(t, red[w]);
        maxp[b * PB + blockIdx.x] = sqrtf(t);  // sqrt monotone: sqrt(max r^2) == max radius
    }
}

// ---- K3: norm coords + packed (voxel idx << 17 | rank); 4 points/thread ----
__global__ void k_points(const float* __restrict__ coords, const float* __restrict__ part,
                         const float* __restrict__ maxp,
                         float* __restrict__ norm_out, unsigned int* __restrict__ pk,
                         int* __restrict__ counts, int N) {
    const int b = blockIdx.y;
    __shared__ float sp[PB * 3];
    __shared__ float mp[PB];
    for (int x = threadIdx.x; x < PB * 3; x += blockDim.x) sp[x] = part[b * PB * 3 + x];
    for (int x = threadIdx.x; x < PB; x += blockDim.x) mp[x] = maxp[b * PB + x];
    __syncthreads();
    const float invN = 1.0f / (float)N;
    float mean[3] = {0.f, 0.f, 0.f};
    float mrad = 0.f;
    for (int x = 0; x < PB; ++x) {
        mean[0] += sp[x * 3]; mean[1] += sp[x * 3 + 1]; mean[2] += sp[x * 3 + 2];
        mrad = fmaxf(mrad, mp[x]);
    }
    const float scale = 2.0f * mrad;
    const float m0 = mean[0] * invN, m1 = mean[1] * invN, m2 = mean[2] * invN;

    const int i = blockIdx.x * blockDim.x + threadIdx.x;  // float4 index
    const int n0 = i * 4;
    if (n0 >= N) return;
    const float* cb = coords + (size_t)b * 3 * N;
    float* nb = norm_out + (size_t)b * 3 * N;
    int* cnts = counts + b * R3V;

    if (n0 + 4 <= N) {
        float4 cx = ((const float4*)cb)[i];
        float4 cy = ((const float4*)(cb + N))[i];
        float4 cz = ((const float4*)(cb + 2 * N))[i];
        float nx[4] = {cx.x, cx.y, cx.z, cx.w};
        float ny[4] = {cy.x, cy.y, cy.z, cy.w};
        float nz[4] = {cz.x, cz.y, cz.z, cz.w};
        int flat[4];
#pragma unroll
        for (int k = 0; k < 4; ++k) {
            float a = fminf(fmaxf(((nx[k] - m0) / scale + 0.5f) * (float)RESV, 0.0f), (float)(RESV - 1));
            float bq = fminf(fmaxf(((ny[k] - m1) / scale + 0.5f) * (float)RESV, 0.0f), (float)(RESV - 1));
            float c = fminf(fmaxf(((nz[k] - m2) / scale + 0.5f) * (float)RESV, 0.0f), (float)(RESV - 1));
            nx[k] = a; ny[k] = bq; nz[k] = c;
            flat[k] = ((int)rintf(a) * RESV + (int)rintf(bq)) * RESV + (int)rintf(c);
        }
        ((float4*)(nb))[i]         = make_float4(nx[0], nx[1], nx[2], nx[3]);
        ((float4*)(nb + N))[i]     = make_float4(ny[0], ny[1], ny[2], ny[3]);
        ((float4*)(nb + 2 * N))[i] = make_float4(nz[0], nz[1], nz[2], nz[3]);
        uint4 o;
        o.x = ((unsigned int)flat[0] << 17) | (unsigned int)atomicAdd(&cnts[flat[0]], 1);
        o.y = ((unsigned int)flat[1] << 17) | (unsigned int)atomicAdd(&cnts[flat[1]], 1);
        o.z = ((unsigned int)flat[2] << 17) | (unsigned int)atomicAdd(&cnts[flat[2]], 1);
        o.w = ((unsigned int)flat[3] << 17) | (unsigned int)atomicAdd(&cnts[flat[3]], 1);
        ((uint4*)(pk + (size_t)b * N))[i] = o;
    } else {
        for (int n = n0; n < N; ++n) {
            int flat = 0;
            float v[3] = {cb[n], cb[N + n], cb[2 * N + n]};
            float m[3] = {m0, m1, m2};
#pragma unroll
            for (int d = 0; d < 3; ++d) {
                float nc = fminf(fmaxf(((v[d] - m[d]) / scale + 0.5f) * (float)RESV, 0.0f),
                                 (float)(RESV - 1));
                nb[d * N + n] = nc;
                flat = flat * RESV + (int)rintf(nc);
            }
            const int jl = atomicAdd(&cnts[flat], 1);
            pk[(size_t)b * N + n] = ((unsigned int)flat << 17) | (unsigned int)jl;
        }
    }
}

// ---- K4: per-batch exclusive scan of counts -> start (stride R3P1, sentinel) ----
__global__ __launch_bounds__(1024, 1) void k_scan(const int* __restrict__ counts,
                                                  int* __restrict__ start, int N) {
    const int b = blockIdx.x;
    const int t = threadIdx.x;
    const int base  = b * R3V + t * 32;
    const int baseS = b * R3P1 + t * 32;
    int c[32];
    int T = 0;
#pragma unroll
    for (int i = 0; i < 32; ++i) { c[i] = counts[base + i]; T += c[i]; }
    int incl = T;
    const int lane = t & 63;
    for (int off = 1; off < 64; off <<= 1) {
        int y = __shfl_up(incl, off);
        if (lane >= off) incl += y;
    }
    __shared__ int wsum[16];
    __shared__ int wbase[16];
    const int w = t >> 6;
    if (lane == 63) wsum[w] = incl;
    __syncthreads();
    if (t == 0) {
        int run = 0;
        for (int i = 0; i < 16; ++i) { wbase[i] = run; run += wsum[i]; }
    }
    __syncthreads();
    int run = wbase[w] + incl - T;  // exclusive prefix
#pragma unroll
    for (int i = 0; i < 32; ++i) {
        start[baseS + i] = run;
        run += c[i];
    }
    if (t == 1023) start[b * R3P1 + R3V] = run;  // == N
}

// ---- K5: feats [B,64,N] fp32 -> fTs [B,N,64] bf16, rows in sorted order ----
__global__ __launch_bounds__(1024, 2) void k_transpose_perm(
        const float* __restrict__ feats, const unsigned int* __restrict__ pk,
        const int* __restrict__ startv,
        unsigned int* __restrict__ fTs32, int* __restrict__ voxid, int N) {
    __shared__ unsigned short tile[256][66];
    __shared__ int jrow[256];
    const int b  = blockIdx.y;
    const int n0 = blockIdx.x * 256;
    const int t  = threadIdx.x;
    const float* fb = feats + (size_t)b * 64 * N;

    const int c = t >> 4;
    const int q = t & 15;
    if (n0 + 256 <= N) {
#pragma unroll
        for (int i = 0; i < 4; ++i) {
            const int nn = q * 4 + i * 64;
            const float4 f = *(const float4*)(fb + (size_t)c * N + n0 + nn);
            tile[nn + 0][c] = f2bf(f.x);
            tile[nn + 1][c] = f2bf(f.y);
            tile[nn + 2][c] = f2bf(f.z);
            tile[nn + 3][c] = f2bf(f.w);
        }
    } else {
        for (int i = 0; i < 4; ++i) {
            const int nn = q * 4 + i * 64;
            for (int u = 0; u < 4; ++u) {
                const int n = n0 + nn + u;
                tile[nn + u][c] = f2bf((n < N) ? fb[(size_t)c * N + n] : 0.f);
            }
        }
    }
    if (t < 256) {
        const int n = n0 + t;
        if (n < N) {
            const unsigned int p = pk[(size_t)b * N + n];
            const int v = (int)(p >> 17);
            const int j = startv[(size_t)b * R3P1 + v] + (int)(p & 0x1FFFFu);
            jrow[t] = j;
            voxid[(size_t)b * N + j] = v;
        }
    }
    __syncthreads();

    // permuted store: 4 passes, 4 rows per wave instruction, 8B/lane
    const int wv   = t >> 6;
    const int lane = t & 63;
    const int lc   = lane & 15;     // channel quad
    const int pr   = lane >> 4;     // row within 4-row group
    uint2* fo2 = (uint2*)fTs32 + (size_t)b * N * 16;
#pragma unroll
    for (int k = 0; k < 4; ++k) {
        const int p = k * 64 + wv * 4 + pr;
        if (n0 + p < N) {
            const uint2 d = *(const uint2*)&tile[p][4 * lc];
            fo2[(size_t)jrow[p] * 16 + lc] = d;
        }
    }
}

// ---- K6: atomic-free segmented reduction over sorted rows (2D grid) ----
__global__ __launch_bounds__(256) void k_gather4(const unsigned int* __restrict__ fTs32,
                                                 const int* __restrict__ voxid,
                                                 const int* __restrict__ startv,
                                                 unsigned int* __restrict__ gridT2,
                                                 int N, int nchunk) {
    const int w     = threadIdx.x >> 6;
    const int lane  = threadIdx.x & 63;
    const int p     = lane >> 4;   // row parity 0..3
    const int lc    = lane & 15;   // channel quad
    const int chunk = blockIdx.x * 4 + w;
    if (chunk >= nchunk) return;
    const int b    = blockIdx.y;
    const int c0   = chunk * CH;
    const int end0 = min(c0 + CH, N);
    const uint2* fb = (const uint2*)(fTs32 + (size_t)b * N * 32);
    const int* vi = voxid  + (size_t)b * N;
    const int* sv = startv + (size_t)b * R3P1;
    uint2* gT = (uint2*)(gridT2) + (size_t)b * R3V * 16;

    int j;
    {
        const int v = vi[c0];
        const int s = sv[v];
        j = (s < c0) ? sv[v + 1] : s;
    }
    while (j < end0) {
        const int v = vi[j];           // wave-uniform
        const int e = sv[v + 1];
        float a0 = 0.f, a1 = 0.f, a2 = 0.f, a3 = 0.f;
        int r = j + p;
        for (; r + 12 < e; r += 16) {  // 4 uint2 loads in flight per lane
            const uint2 u0 = fb[(size_t)(r + 0) * 16 + lc];
            const uint2 u1 = fb[(size_t)(r + 4) * 16 + lc];
            const uint2 u2 = fb[(size_t)(r + 8) * 16 + lc];
            const uint2 u3 = fb[(size_t)(r + 12) * 16 + lc];
            a0 += (blo(u0.x) + blo(u1.x)) + (blo(u2.x) + blo(u3.x));
            a1 += (bhi(u0.x) + bhi(u1.x)) + (bhi(u2.x) + bhi(u3.x));
            a2 += (blo(u0.y) + blo(u1.y)) + (blo(u2.y) + blo(u3.y));
            a3 += (bhi(u0.y) + bhi(u1.y)) + (bhi(u2.y) + bhi(u3.y));
        }
        for (; r < e; r += 4) {
            const uint2 u = fb[(size_t)r * 16 + lc];
            a0 += blo(u.x);
            a1 += bhi(u.x);
            a2 += blo(u.y);
            a3 += bhi(u.y);
        }
        a0 += __shfl_xor(a0, 16); a0 += __shfl_xor(a0, 32);
        a1 += __shfl_xor(a1, 16); a1 += __shfl_xor(a1, 32);
        a2 += __shfl_xor(a2, 16); a2 += __shfl_xor(a2, 32);
        a3 += __shfl_xor(a3, 16); a3 += __shfl_xor(a3, 32);
        if (p == 0) {
            gT[(size_t)v * 16 + lc] = make_uint2(pkbf(a0, a1), pkbf(a2, a3));
        }
        j = e;
    }
}

// ---- K7: gridT bf16 [B,R3,64] -> grid fp32 [B,64,R3], /cnt, cnt==0 -> 0 ----
__global__ __launch_bounds__(256) void k_fin(const unsigned int* __restrict__ gridT2,
                                             const int* __restrict__ counts,
                                             float* __restrict__ grid) {
    __shared__ float tile[64][65];
    const int b    = blockIdx.y;
    const int v0   = blockIdx.x * 64;
    const int t    = threadIdx.x;
    const int lane = t & 63;
    const int w    = t >> 6;
    const unsigned int* g = gridT2 + ((size_t)b * R3V + v0) * 32;
#pragma unroll
    for (int k = 0; k < 8; ++k) {
        const int i  = t + k * 256;  // v*32 + cd
        const int v  = i >> 5;
        const int cd = i & 31;
        const unsigned int u = g[i];
        tile[v][2 * cd]     = blo(u);
        tile[v][2 * cd + 1] = bhi(u);
    }
    __syncthreads();
    const int cnt  = counts[(size_t)b * R3V + v0 + lane];
    const float rc = 1.0f / fmaxf((float)cnt, 1.0f);
    const bool occ = cnt > 0;
    float* gb = grid + (size_t)b * 64 * R3V;
#pragma unroll
    for (int k = 0; k < 16; ++k) {
        const int c = w + k * 4;
        gb[(size_t)c * R3V + v0 + lane] = occ ? tile[lane][c] * rc : 0.0f;
    }
}

// ============================ fallback: LDS-atomic scatter ============================

__device__ __forceinline__ int swz(int v) {
    return v ^ ((v >> 5) & 31) ^ ((v >> 10) & 31);
}

__global__ void k_recip_fb(const int* __restrict__ cnt, float* __restrict__ recip, int total) {
    const int i = blockIdx.x * blockDim.x + threadIdx.x;
    if (i < total) recip[i] = 1.0f / fmaxf((float)cnt[i], 1.0f);
}

__global__ __launch_bounds__(1024, 1) void k_scatter_lds(
        const float* __restrict__ feats, const unsigned int* __restrict__ pk,
        const float* __restrict__ recip, float* __restrict__ grid, int N, int C) {
    extern __shared__ float acc[];
    const int bc  = blockIdx.x;
    const int b   = bc / C;
    const int tid = threadIdx.x;
    for (int i = tid * 4; i < R3V; i += blockDim.x * 4)
        *(float4*)(acc + i) = make_float4(0.f, 0.f, 0.f, 0.f);
    __syncthreads();
    const float* fb = feats + (size_t)bc * N;
    const unsigned int* ib = pk + (size_t)b * N;
    for (int n = tid; n < N; n += blockDim.x) atomicAdd(&acc[swz((int)(ib[n] >> 17))], fb[n]);
    __syncthreads();
    const float* rb = recip + (size_t)b * R3V;
    float*       gb = grid  + (size_t)bc * R3V;
    for (int i = tid; i < R3V; i += blockDim.x)
        gb[i] = acc[swz(i)] * rb[i];
}

// ============================ launch ============================

extern "C" void kernel_launch(void* const* d_in, const int* in_sizes, int n_in,
                              void* d_out, int out_size, void* d_ws, size_t ws_size,
                              hipStream_t stream) {
    const float* feats  = (const float*)d_in[0];
    const float* coords = (const float*)d_in[1];

    const long long s0 = in_sizes[0], s1 = in_sizes[1];
    const int BC = (int)(((long long)out_size - s1) / R3V);  // B*C
    const int N  = (int)(s0 / BC);
    const int B  = (int)(s1 / (3LL * N));
    const int C  = BC / B;

    float* out_grid = (float*)d_out;               // [B, C, R3]
    float* out_norm = out_grid + (size_t)BC * R3V; // [B, 3, N]

    // ws layout (float32 slots). Header = 4096 floats (PB=128 partials).
    const size_t BR3 = (size_t)B * R3V;
    const size_t BN  = (size_t)B * N;
    const size_t o_counts = 4096;
    const size_t o_start  = o_counts + BR3;
    const size_t o_recip  = o_start + (size_t)B * R3P1;  // fallback only
    const size_t o_pk     = o_recip + BR3;
    const size_t o_voxid  = o_pk + BN;
    size_t o_gridT = (o_voxid + BN + 63) & ~(size_t)63;        // bf16: BR3*32 slots
    size_t o_fTs   = (o_gridT + BR3 * 32 + 63) & ~(size_t)63;  // bf16: BN*32 slots
    const size_t need = (o_fTs + BN * 32) * sizeof(float);

    float*        ws_part = (float*)d_ws;                  // [B*PB*3]
    float*        ws_maxp = (float*)d_ws + 3072;           // [B*PB]
    int*          counts  = (int*)d_ws + o_counts;
    int*          startv  = (int*)d_ws + o_start;
    float*        recip   = (float*)d_ws + o_recip;
    unsigned int* pk      = (unsigned int*)d_ws + o_pk;
    int*          voxid   = (int*)d_ws + o_voxid;
    unsigned int* gridT2  = (unsigned int*)((float*)d_ws + o_gridT);
    unsigned int* fTs32   = (unsigned int*)((float*)d_ws + o_fTs);

    const int BLK = 256;
    const int nInt4 = (int)(BR3 / 4);
    dim3 gRed(PB, B);
    // k_sums also zeroes counts (guarded; PB*B*256 threads >= BR3/4)
    k_sums<<<gRed, BLK, 0, stream>>>(coords, ws_part, (int4*)counts, nInt4, N);
    k_maxrad<<<gRed, BLK, 0, stream>>>(coords, ws_part, ws_maxp, N);

    const int nQuads = (N + 3) / 4;
    dim3 gPts((nQuads + BLK - 1) / BLK, B);
    k_points<<<gPts, BLK, 0, stream>>>(coords, ws_part, ws_maxp, out_norm, pk, counts, N);

    if (ws_size >= need && C == 64) {
        k_scan<<<dim3(B), 1024, 0, stream>>>(counts, startv, N);
        dim3 gT((N + 255) / 256, B);
        k_transpose_perm<<<gT, 1024, 0, stream>>>(feats, pk, startv, fTs32, voxid, N);
        const int nchunk = (N + CH - 1) / CH;
        dim3 gG((nchunk + 3) / 4, B);
        k_gather4<<<gG, 256, 0, stream>>>(fTs32, voxid, startv, gridT2, N, nchunk);
        dim3 gF(R3V / 64, B);
        k_fin<<<gF, 256, 0, stream>>>(gridT2, counts, out_grid);
    } else {
        const int tot = B * R3V;
        k_recip_fb<<<(tot + BLK - 1) / BLK, BLK, 0, stream>>>(counts, recip, tot);
        k_scatter_lds<<<dim3(BC), 1024, R3V * sizeof(float), stream>>>(
            feats, pk, recip, out_grid, N, C);
    }
}

// Round 16
// 191.374 us; speedup vs baseline: 1.1708x; 1.0234x over previous
//
#include <hip/hip_runtime.h>
#include <hip/hip_bf16.h>

#define RESV 32
#define R3V (RESV * RESV * RESV)
#define R3P1 (R3V + 1)
#define CH 16    // sorted points per wave-chunk in k_gather4 (R16 experiment; R15=32)
#define PB 128   // partial-reduction blocks per batch (occupancy: 4 blocks/CU)

__device__ __forceinline__ unsigned short f2bf(float f) {
    __hip_bfloat16 h = __float2bfloat16(f);  // RNE
    unsigned short u;
    __builtin_memcpy(&u, &h, 2);
    return u;
}
__device__ __forceinline__ unsigned int pkbf(float lo, float hi) {
    return (unsigned int)f2bf(lo) | ((unsigned int)f2bf(hi) << 16);
}
__device__ __forceinline__ float blo(unsigned int u) { return __uint_as_float(u << 16); }
__device__ __forceinline__ float bhi(unsigned int u) { return __uint_as_float(u & 0xffff0000u); }

// ws header (floats): [0, 3072) per-batch sum partials part[b*PB*3 + x*3 + d] (PB=128)
//                     [3072, 4096) per-batch max partials maxp[b*PB + x]

// ---- K1: per-batch per-block coordinate sums -> partials (no atomics, float4) ----
// Also zeroes counts (stream-ordered before k_points; distinct buffer).
__global__ void k_sums(const float* __restrict__ coords, float* __restrict__ part,
                       int4* __restrict__ counts4, int nInt4, int N) {
    const int b = blockIdx.y;
    {
        const int g = (blockIdx.y * gridDim.x + blockIdx.x) * blockDim.x + threadIdx.x;
        if (g < nInt4) counts4[g] = make_int4(0, 0, 0, 0);
    }
    const float* cb = coords + (size_t)b * 3 * N;
    const int N4 = N >> 2;
    float sx = 0.f, sy = 0.f, sz = 0.f;
    for (int i = blockIdx.x * blockDim.x + threadIdx.x; i < N4; i += gridDim.x * blockDim.x) {
        const float4 x = ((const float4*)cb)[i];
        const float4 y = ((const float4*)(cb + N))[i];
        const float4 z = ((const float4*)(cb + 2 * N))[i];
        sx += (x.x + x.y) + (x.z + x.w);
        sy += (y.x + y.y) + (y.z + y.w);
        sz += (z.x + z.y) + (z.z + z.w);
    }
    for (int n = 4 * N4 + blockIdx.x * blockDim.x + threadIdx.x; n < N;
         n += gridDim.x * blockDim.x) {
        sx += cb[n];
        sy += cb[N + n];
        sz += cb[2 * N + n];
    }
    for (int off = 32; off > 0; off >>= 1) {
        sx += __shfl_down(sx, off);
        sy += __shfl_down(sy, off);
        sz += __shfl_down(sz, off);
    }
    __shared__ float red[3][4];
    const int lane = threadIdx.x & 63;
    const int wv   = threadIdx.x >> 6;
    if (lane == 0) { red[0][wv] = sx; red[1][wv] = sy; red[2][wv] = sz; }
    __syncthreads();
    if (threadIdx.x == 0) {
        float tx = 0.f, ty = 0.f, tz = 0.f;
        const int nw = blockDim.x >> 6;
        for (int w = 0; w < nw; ++w) { tx += red[0][w]; ty += red[1][w]; tz += red[2][w]; }
        float* p = part + (b * PB + blockIdx.x) * 3;
        p[0] = tx; p[1] = ty; p[2] = tz;
    }
}

// ---- K2: per-batch per-block max radius -> partials (no atomics, float4) ----
__global__ void k_maxrad(const float* __restrict__ coords, const float* __restrict__ part,
                         float* __restrict__ maxp, int N) {
    const int b = blockIdx.y;
    __shared__ float sp[PB * 3];
    for (int x = threadIdx.x; x < PB * 3; x += blockDim.x) sp[x] = part[b * PB * 3 + x];
    __syncthreads();
    const float invN = 1.0f / (float)N;
    float mx = 0.f, my = 0.f, mz = 0.f;
    for (int x = 0; x < PB; ++x) { mx += sp[x * 3]; my += sp[x * 3 + 1]; mz += sp[x * 3 + 2]; }
    mx *= invN; my *= invN; mz *= invN;

    const float* cb = coords + (size_t)b * 3 * N;
    const int N4 = N >> 2;
    float r = 0.f;
    for (int i = blockIdx.x * blockDim.x + threadIdx.x; i < N4; i += gridDim.x * blockDim.x) {
        const float4 x = ((const float4*)cb)[i];
        const float4 y = ((const float4*)(cb + N))[i];
        const float4 z = ((const float4*)(cb + 2 * N))[i];
        const float dx0 = x.x - mx, dy0 = y.x - my, dz0 = z.x - mz;
        const float dx1 = x.y - mx, dy1 = y.y - my, dz1 = z.y - mz;
        const float dx2 = x.z - mx, dy2 = y.z - my, dz2 = z.z - mz;
        const float dx3 = x.w - mx, dy3 = y.w - my, dz3 = z.w - mz;
        const float r0 = dx0 * dx0 + dy0 * dy0 + dz0 * dz0;
        const float r1 = dx1 * dx1 + dy1 * dy1 + dz1 * dz1;
        const float r2 = dx2 * dx2 + dy2 * dy2 + dz2 * dz2;
        const float r3 = dx3 * dx3 + dy3 * dy3 + dz3 * dz3;
        r = fmaxf(r, fmaxf(fmaxf(r0, r1), fmaxf(r2, r3)));
    }
    for (int n = 4 * N4 + blockIdx.x * blockDim.x + threadIdx.x; n < N;
         n += gridDim.x * blockDim.x) {
        const float dx = cb[n] - mx;
        const float dy = cb[N + n] - my;
        const float dz = cb[2 * N + n] - mz;
        r = fmaxf(r, dx * dx + dy * dy + dz * dz);
    }
    for (int off = 32; off > 0; off >>= 1) r = fmaxf(r, __shfl_down(r, off));
    __shared__ float red[4];
    const int lane = threadIdx.x & 63;
    const int wv   = threadIdx.x >> 6;
    if (lane == 0) red[wv] = r;
    __syncthreads();
    if (threadIdx.x == 0) {
        const int nw = blockDim.x >> 6;
        float t = 0.f;
        for (int w = 0; w < nw; ++w) t = fmaxf(t, red[w]);
        maxp[b * PB + blockIdx.x] = sqrtf(t);  // sqrt monotone: sqrt(max r^2) == max radius
    }
}

// ---- K3: norm coords + packed (voxel idx << 17 | rank); 4 points/thread ----
__global__ void k_points(const float* __restrict__ coords, const float* __restrict__ part,
                         const float* __restrict__ maxp,
                         float* __restrict__ norm_out, unsigned int* __restrict__ pk,
                         int* __restrict__ counts, int N) {
    const int b = blockIdx.y;
    __shared__ float sp[PB * 3];
    __shared__ float mp[PB];
    for (int x = threadIdx.x; x < PB * 3; x += blockDim.x) sp[x] = part[b * PB * 3 + x];
    for (int x = threadIdx.x; x < PB; x += blockDim.x) mp[x] = maxp[b * PB + x];
    __syncthreads();
    const float invN = 1.0f / (float)N;
    float mean[3] = {0.f, 0.f, 0.f};
    float mrad = 0.f;
    for (int x = 0; x < PB; ++x) {
        mean[0] += sp[x * 3]; mean[1] += sp[x * 3 + 1]; mean[2] += sp[x * 3 + 2];
        mrad = fmaxf(mrad, mp[x]);
    }
    const float scale = 2.0f * mrad;
    const float m0 = mean[0] * invN, m1 = mean[1] * invN, m2 = mean[2] * invN;

    const int i = blockIdx.x * blockDim.x + threadIdx.x;  // float4 index
    const int n0 = i * 4;
    if (n0 >= N) return;
    const float* cb = coords + (size_t)b * 3 * N;
    float* nb = norm_out + (size_t)b * 3 * N;
    int* cnts = counts + b * R3V;

    if (n0 + 4 <= N) {
        float4 cx = ((const float4*)cb)[i];
        float4 cy = ((const float4*)(cb + N))[i];
        float4 cz = ((const float4*)(cb + 2 * N))[i];
        float nx[4] = {cx.x, cx.y, cx.z, cx.w};
        float ny[4] = {cy.x, cy.y, cy.z, cy.w};
        float nz[4] = {cz.x, cz.y, cz.z, cz.w};
        int flat[4];
#pragma unroll
        for (int k = 0; k < 4; ++k) {
            float a = fminf(fmaxf(((nx[k] - m0) / scale + 0.5f) * (float)RESV, 0.0f), (float)(RESV - 1));
            float bq = fminf(fmaxf(((ny[k] - m1) / scale + 0.5f) * (float)RESV, 0.0f), (float)(RESV - 1));
            float c = fminf(fmaxf(((nz[k] - m2) / scale + 0.5f) * (float)RESV, 0.0f), (float)(RESV - 1));
            nx[k] = a; ny[k] = bq; nz[k] = c;
            flat[k] = ((int)rintf(a) * RESV + (int)rintf(bq)) * RESV + (int)rintf(c);
        }
        ((float4*)(nb))[i]         = make_float4(nx[0], nx[1], nx[2], nx[3]);
        ((float4*)(nb + N))[i]     = make_float4(ny[0], ny[1], ny[2], ny[3]);
        ((float4*)(nb + 2 * N))[i] = make_float4(nz[0], nz[1], nz[2], nz[3]);
        uint4 o;
        o.x = ((unsigned int)flat[0] << 17) | (unsigned int)atomicAdd(&cnts[flat[0]], 1);
        o.y = ((unsigned int)flat[1] << 17) | (unsigned int)atomicAdd(&cnts[flat[1]], 1);
        o.z = ((unsigned int)flat[2] << 17) | (unsigned int)atomicAdd(&cnts[flat[2]], 1);
        o.w = ((unsigned int)flat[3] << 17) | (unsigned int)atomicAdd(&cnts[flat[3]], 1);
        ((uint4*)(pk + (size_t)b * N))[i] = o;
    } else {
        for (int n = n0; n < N; ++n) {
            int flat = 0;
            float v[3] = {cb[n], cb[N + n], cb[2 * N + n]};
            float m[3] = {m0, m1, m2};
#pragma unroll
            for (int d = 0; d < 3; ++d) {
                float nc = fminf(fmaxf(((v[d] - m[d]) / scale + 0.5f) * (float)RESV, 0.0f),
                                 (float)(RESV - 1));
                nb[d * N + n] = nc;
                flat = flat * RESV + (int)rintf(nc);
            }
            const int jl = atomicAdd(&cnts[flat], 1);
            pk[(size_t)b * N + n] = ((unsigned int)flat << 17) | (unsigned int)jl;
        }
    }
}

// ---- K4: per-batch exclusive scan of counts -> start (stride R3P1, sentinel) ----
__global__ __launch_bounds__(1024, 1) void k_scan(const int* __restrict__ counts,
                                                  int* __restrict__ start, int N) {
    const int b = blockIdx.x;
    const int t = threadIdx.x;
    const int base  = b * R3V + t * 32;
    const int baseS = b * R3P1 + t * 32;
    int c[32];
    int T = 0;
#pragma unroll
    for (int i = 0; i < 32; ++i) { c[i] = counts[base + i]; T += c[i]; }
    int incl = T;
    const int lane = t & 63;
    for (int off = 1; off < 64; off <<= 1) {
        int y = __shfl_up(incl, off);
        if (lane >= off) incl += y;
    }
    __shared__ int wsum[16];
    __shared__ int wbase[16];
    const int w = t >> 6;
    if (lane == 63) wsum[w] = incl;
    __syncthreads();
    if (t == 0) {
        int run = 0;
        for (int i = 0; i < 16; ++i) { wbase[i] = run; run += wsum[i]; }
    }
    __syncthreads();
    int run = wbase[w] + incl - T;  // exclusive prefix
#pragma unroll
    for (int i = 0; i < 32; ++i) {
        start[baseS + i] = run;
        run += c[i];
    }
    if (t == 1023) start[b * R3P1 + R3V] = run;  // == N
}

// ---- K5: feats [B,64,N] fp32 -> fTs [B,N,64] bf16, rows in sorted order ----
__global__ __launch_bounds__(1024, 2) void k_transpose_perm(
        const float* __restrict__ feats, const unsigned int* __restrict__ pk,
        const int* __restrict__ startv,
        unsigned int* __restrict__ fTs32, int* __restrict__ voxid, int N) {
    __shared__ unsigned short tile[256][66];
    __shared__ int jrow[256];
    const int b  = blockIdx.y;
    const int n0 = blockIdx.x * 256;
    const int t  = threadIdx.x;
    const float* fb = feats + (size_t)b * 64 * N;

    const int c = t >> 4;
    const int q = t & 15;
    if (n0 + 256 <= N) {
#pragma unroll
        for (int i = 0; i < 4; ++i) {
            const int nn = q * 4 + i * 64;
            const float4 f = *(const float4*)(fb + (size_t)c * N + n0 + nn);
            tile[nn + 0][c] = f2bf(f.x);
            tile[nn + 1][c] = f2bf(f.y);
            tile[nn + 2][c] = f2bf(f.z);
            tile[nn + 3][c] = f2bf(f.w);
        }
    } else {
        for (int i = 0; i < 4; ++i) {
            const int nn = q * 4 + i * 64;
            for (int u = 0; u < 4; ++u) {
                const int n = n0 + nn + u;
                tile[nn + u][c] = f2bf((n < N) ? fb[(size_t)c * N + n] : 0.f);
            }
        }
    }
    if (t < 256) {
        const int n = n0 + t;
        if (n < N) {
            const unsigned int p = pk[(size_t)b * N + n];
            const int v = (int)(p >> 17);
            const int j = startv[(size_t)b * R3P1 + v] + (int)(p & 0x1FFFFu);
            jrow[t] = j;
            voxid[(size_t)b * N + j] = v;
        }
    }
    __syncthreads();

    // permuted store: 4 passes, 4 rows per wave instruction, 8B/lane
    const int wv   = t >> 6;
    const int lane = t & 63;
    const int lc   = lane & 15;     // channel quad
    const int pr   = lane >> 4;     // row within 4-row group
    uint2* fo2 = (uint2*)fTs32 + (size_t)b * N * 16;
#pragma unroll
    for (int k = 0; k < 4; ++k) {
        const int p = k * 64 + wv * 4 + pr;
        if (n0 + p < N) {
            const uint2 d = *(const uint2*)&tile[p][4 * lc];
            fo2[(size_t)jrow[p] * 16 + lc] = d;
        }
    }
}

// ---- K6: atomic-free segmented reduction over sorted rows (2D grid) ----
__global__ __launch_bounds__(256) void k_gather4(const unsigned int* __restrict__ fTs32,
                                                 const int* __restrict__ voxid,
                                                 const int* __restrict__ startv,
                                                 unsigned int* __restrict__ gridT2,
                                                 int N, int nchunk) {
    const int w     = threadIdx.x >> 6;
    const int lane  = threadIdx.x & 63;
    const int p     = lane >> 4;   // row parity 0..3
    const int lc    = lane & 15;   // channel quad
    const int chunk = blockIdx.x * 4 + w;
    if (chunk >= nchunk) return;
    const int b    = blockIdx.y;
    const int c0   = chunk * CH;
    const int end0 = min(c0 + CH, N);
    const uint2* fb = (const uint2*)(fTs32 + (size_t)b * N * 32);
    const int* vi = voxid  + (size_t)b * N;
    const int* sv = startv + (size_t)b * R3P1;
    uint2* gT = (uint2*)(gridT2) + (size_t)b * R3V * 16;

    int j;
    {
        const int v = vi[c0];
        const int s = sv[v];
        j = (s < c0) ? sv[v + 1] : s;
    }
    while (j < end0) {
        const int v = vi[j];           // wave-uniform
        const int e = sv[v + 1];
        float a0 = 0.f, a1 = 0.f, a2 = 0.f, a3 = 0.f;
        int r = j + p;
        for (; r + 12 < e; r += 16) {  // 4 uint2 loads in flight per lane
            const uint2 u0 = fb[(size_t)(r + 0) * 16 + lc];
            const uint2 u1 = fb[(size_t)(r + 4) * 16 + lc];
            const uint2 u2 = fb[(size_t)(r + 8) * 16 + lc];
            const uint2 u3 = fb[(size_t)(r + 12) * 16 + lc];
            a0 += (blo(u0.x) + blo(u1.x)) + (blo(u2.x) + blo(u3.x));
            a1 += (bhi(u0.x) + bhi(u1.x)) + (bhi(u2.x) + bhi(u3.x));
            a2 += (blo(u0.y) + blo(u1.y)) + (blo(u2.y) + blo(u3.y));
            a3 += (bhi(u0.y) + bhi(u1.y)) + (bhi(u2.y) + bhi(u3.y));
        }
        for (; r < e; r += 4) {
            const uint2 u = fb[(size_t)r * 16 + lc];
            a0 += blo(u.x);
            a1 += bhi(u.x);
            a2 += blo(u.y);
            a3 += bhi(u.y);
        }
        a0 += __shfl_xor(a0, 16); a0 += __shfl_xor(a0, 32);
        a1 += __shfl_xor(a1, 16); a1 += __shfl_xor(a1, 32);
        a2 += __shfl_xor(a2, 16); a2 += __shfl_xor(a2, 32);
        a3 += __shfl_xor(a3, 16); a3 += __shfl_xor(a3, 32);
        if (p == 0) {
            gT[(size_t)v * 16 + lc] = make_uint2(pkbf(a0, a1), pkbf(a2, a3));
        }
        j = e;
    }
}

// ---- K7: gridT bf16 [B,R3,64] -> grid fp32 [B,64,R3], /cnt, cnt==0 -> 0 ----
__global__ __launch_bounds__(256) void k_fin(const unsigned int* __restrict__ gridT2,
                                             const int* __restrict__ counts,
                                             float* __restrict__ grid) {
    __shared__ float tile[64][65];
    const int b    = blockIdx.y;
    const int v0   = blockIdx.x * 64;
    const int t    = threadIdx.x;
    const int lane = t & 63;
    const int w    = t >> 6;
    const unsigned int* g = gridT2 + ((size_t)b * R3V + v0) * 32;
#pragma unroll
    for (int k = 0; k < 8; ++k) {
        const int i  = t + k * 256;  // v*32 + cd
        const int v  = i >> 5;
        const int cd = i & 31;
        const unsigned int u = g[i];
        tile[v][2 * cd]     = blo(u);
        tile[v][2 * cd + 1] = bhi(u);
    }
    __syncthreads();
    const int cnt  = counts[(size_t)b * R3V + v0 + lane];
    const float rc = 1.0f / fmaxf((float)cnt, 1.0f);
    const bool occ = cnt > 0;
    float* gb = grid + (size_t)b * 64 * R3V;
#pragma unroll
    for (int k = 0; k < 16; ++k) {
        const int c = w + k * 4;
        gb[(size_t)c * R3V + v0 + lane] = occ ? tile[lane][c] * rc : 0.0f;
    }
}

// ============================ fallback: LDS-atomic scatter ============================

__device__ __forceinline__ int swz(int v) {
    return v ^ ((v >> 5) & 31) ^ ((v >> 10) & 31);
}

__global__ void k_recip_fb(const int* __restrict__ cnt, float* __restrict__ recip, int total) {
    const int i = blockIdx.x * blockDim.x + threadIdx.x;
    if (i < total) recip[i] = 1.0f / fmaxf((float)cnt[i], 1.0f);
}

__global__ __launch_bounds__(1024, 1) void k_scatter_lds(
        const float* __restrict__ feats, const unsigned int* __restrict__ pk,
        const float* __restrict__ recip, float* __restrict__ grid, int N, int C) {
    extern __shared__ float acc[];
    const int bc  = blockIdx.x;
    const int b   = bc / C;
    const int tid = threadIdx.x;
    for (int i = tid * 4; i < R3V; i += blockDim.x * 4)
        *(float4*)(acc + i) = make_float4(0.f, 0.f, 0.f, 0.f);
    __syncthreads();
    const float* fb = feats + (size_t)bc * N;
    const unsigned int* ib = pk + (size_t)b * N;
    for (int n = tid; n < N; n += blockDim.x) atomicAdd(&acc[swz((int)(ib[n] >> 17))], fb[n]);
    __syncthreads();
    const float* rb = recip + (size_t)b * R3V;
    float*       gb = grid  + (size_t)bc * R3V;
    for (int i = tid; i < R3V; i += blockDim.x)
        gb[i] = acc[swz(i)] * rb[i];
}

// ============================ launch ============================

extern "C" void kernel_launch(void* const* d_in, const int* in_sizes, int n_in,
                              void* d_out, int out_size, void* d_ws, size_t ws_size,
                              hipStream_t stream) {
    const float* feats  = (const float*)d_in[0];
    const float* coords = (const float*)d_in[1];

    const long long s0 = in_sizes[0], s1 = in_sizes[1];
    const int BC = (int)(((long long)out_size - s1) / R3V);  // B*C
    const int N  = (int)(s0 / BC);
    const int B  = (int)(s1 / (3LL * N));
    const int C  = BC / B;

    float* out_grid = (float*)d_out;               // [B, C, R3]
    float* out_norm = out_grid + (size_t)BC * R3V; // [B, 3, N]

    // ws layout (float32 slots). Header = 4096 floats (PB=128 partials).
    const size_t BR3 = (size_t)B * R3V;
    const size_t BN  = (size_t)B * N;
    const size_t o_counts = 4096;
    const size_t o_start  = o_counts + BR3;
    const size_t o_recip  = o_start + (size_t)B * R3P1;  // fallback only
    const size_t o_pk     = o_recip + BR3;
    const size_t o_voxid  = o_pk + BN;
    size_t o_gridT = (o_voxid + BN + 63) & ~(size_t)63;        // bf16: BR3*32 slots
    size_t o_fTs   = (o_gridT + BR3 * 32 + 63) & ~(size_t)63;  // bf16: BN*32 slots
    const size_t need = (o_fTs + BN * 32) * sizeof(float);

    float*        ws_part = (float*)d_ws;                  // [B*PB*3]
    float*        ws_maxp = (float*)d_ws + 3072;           // [B*PB]
    int*          counts  = (int*)d_ws + o_counts;
    int*          startv  = (int*)d_ws + o_start;
    float*        recip   = (float*)d_ws + o_recip;
    unsigned int* pk      = (unsigned int*)d_ws + o_pk;
    int*          voxid   = (int*)d_ws + o_voxid;
    unsigned int* gridT2  = (unsigned int*)((float*)d_ws + o_gridT);
    unsigned int* fTs32   = (unsigned int*)((float*)d_ws + o_fTs);

    const int BLK = 256;
    const int nInt4 = (int)(BR3 / 4);
    dim3 gRed(PB, B);
    // k_sums also zeroes counts (guarded; PB*B*256 threads >= BR3/4)
    k_sums<<<gRed, BLK, 0, stream>>>(coords, ws_part, (int4*)counts, nInt4, N);
    k_maxrad<<<gRed, BLK, 0, stream>>>(coords, ws_part, ws_maxp, N);

    const int nQuads = (N + 3) / 4;
    dim3 gPts((nQuads + BLK - 1) / BLK, B);
    k_points<<<gPts, BLK, 0, stream>>>(coords, ws_part, ws_maxp, out_norm, pk, counts, N);

    if (ws_size >= need && C == 64) {
        k_scan<<<dim3(B), 1024, 0, stream>>>(counts, startv, N);
        dim3 gT((N + 255) / 256, B);
        k_transpose_perm<<<gT, 1024, 0, stream>>>(feats, pk, startv, fTs32, voxid, N);
        const int nchunk = (N + CH - 1) / CH;
        dim3 gG((nchunk + 3) / 4, B);
        k_gather4<<<gG, 256, 0, stream>>>(fTs32, voxid, startv, gridT2, N, nchunk);
        dim3 gF(R3V / 64, B);
        k_fin<<<gF, 256, 0, stream>>>(gridT2, counts, out_grid);
    } else {
        const int tot = B * R3V;
        k_recip_fb<<<(tot + BLK - 1) / BLK, BLK, 0, stream>>>(counts, recip, tot);
        k_scatter_lds<<<dim3(BC), 1024, R3V * sizeof(float), stream>>>(
            feats, pk, recip, out_grid, N, C);
    }
}

// Round 17
// 189.879 us; speedup vs baseline: 1.1801x; 1.0079x over previous
//
#include <hip/hip_runtime.h>
#include <hip/hip_bf16.h>

#define RESV 32
#define R3V (RESV * RESV * RESV)
#define R3P1 (R3V + 1)
#define CH 8     // sorted points per wave-chunk in k_gather4 (R17 final probe; R16=16)
#define PB 128   // partial-reduction blocks per batch (occupancy: 4 blocks/CU)

__device__ __forceinline__ unsigned short f2bf(float f) {
    __hip_bfloat16 h = __float2bfloat16(f);  // RNE
    unsigned short u;
    __builtin_memcpy(&u, &h, 2);
    return u;
}
__device__ __forceinline__ unsigned int pkbf(float lo, float hi) {
    return (unsigned int)f2bf(lo) | ((unsigned int)f2bf(hi) << 16);
}
__device__ __forceinline__ float blo(unsigned int u) { return __uint_as_float(u << 16); }
__device__ __forceinline__ float bhi(unsigned int u) { return __uint_as_float(u & 0xffff0000u); }

// ws header (floats): [0, 3072) per-batch sum partials part[b*PB*3 + x*3 + d] (PB=128)
//                     [3072, 4096) per-batch max partials maxp[b*PB + x]

// ---- K1: per-batch per-block coordinate sums -> partials (no atomics, float4) ----
// Also zeroes counts (stream-ordered before k_points; distinct buffer).
__global__ void k_sums(const float* __restrict__ coords, float* __restrict__ part,
                       int4* __restrict__ counts4, int nInt4, int N) {
    const int b = blockIdx.y;
    {
        const int g = (blockIdx.y * gridDim.x + blockIdx.x) * blockDim.x + threadIdx.x;
        if (g < nInt4) counts4[g] = make_int4(0, 0, 0, 0);
    }
    const float* cb = coords + (size_t)b * 3 * N;
    const int N4 = N >> 2;
    float sx = 0.f, sy = 0.f, sz = 0.f;
    for (int i = blockIdx.x * blockDim.x + threadIdx.x; i < N4; i += gridDim.x * blockDim.x) {
        const float4 x = ((const float4*)cb)[i];
        const float4 y = ((const float4*)(cb + N))[i];
        const float4 z = ((const float4*)(cb + 2 * N))[i];
        sx += (x.x + x.y) + (x.z + x.w);
        sy += (y.x + y.y) + (y.z + y.w);
        sz += (z.x + z.y) + (z.z + z.w);
    }
    for (int n = 4 * N4 + blockIdx.x * blockDim.x + threadIdx.x; n < N;
         n += gridDim.x * blockDim.x) {
        sx += cb[n];
        sy += cb[N + n];
        sz += cb[2 * N + n];
    }
    for (int off = 32; off > 0; off >>= 1) {
        sx += __shfl_down(sx, off);
        sy += __shfl_down(sy, off);
        sz += __shfl_down(sz, off);
    }
    __shared__ float red[3][4];
    const int lane = threadIdx.x & 63;
    const int wv   = threadIdx.x >> 6;
    if (lane == 0) { red[0][wv] = sx; red[1][wv] = sy; red[2][wv] = sz; }
    __syncthreads();
    if (threadIdx.x == 0) {
        float tx = 0.f, ty = 0.f, tz = 0.f;
        const int nw = blockDim.x >> 6;
        for (int w = 0; w < nw; ++w) { tx += red[0][w]; ty += red[1][w]; tz += red[2][w]; }
        float* p = part + (b * PB + blockIdx.x) * 3;
        p[0] = tx; p[1] = ty; p[2] = tz;
    }
}

// ---- K2: per-batch per-block max radius -> partials (no atomics, float4) ----
__global__ void k_maxrad(const float* __restrict__ coords, const float* __restrict__ part,
                         float* __restrict__ maxp, int N) {
    const int b = blockIdx.y;
    __shared__ float sp[PB * 3];
    for (int x = threadIdx.x; x < PB * 3; x += blockDim.x) sp[x] = part[b * PB * 3 + x];
    __syncthreads();
    const float invN = 1.0f / (float)N;
    float mx = 0.f, my = 0.f, mz = 0.f;
    for (int x = 0; x < PB; ++x) { mx += sp[x * 3]; my += sp[x * 3 + 1]; mz += sp[x * 3 + 2]; }
    mx *= invN; my *= invN; mz *= invN;

    const float* cb = coords + (size_t)b * 3 * N;
    const int N4 = N >> 2;
    float r = 0.f;
    for (int i = blockIdx.x * blockDim.x + threadIdx.x; i < N4; i += gridDim.x * blockDim.x) {
        const float4 x = ((const float4*)cb)[i];
        const float4 y = ((const float4*)(cb + N))[i];
        const float4 z = ((const float4*)(cb + 2 * N))[i];
        const float dx0 = x.x - mx, dy0 = y.x - my, dz0 = z.x - mz;
        const float dx1 = x.y - mx, dy1 = y.y - my, dz1 = z.y - mz;
        const float dx2 = x.z - mx, dy2 = y.z - my, dz2 = z.z - mz;
        const float dx3 = x.w - mx, dy3 = y.w - my, dz3 = z.w - mz;
        const float r0 = dx0 * dx0 + dy0 * dy0 + dz0 * dz0;
        const float r1 = dx1 * dx1 + dy1 * dy1 + dz1 * dz1;
        const float r2 = dx2 * dx2 + dy2 * dy2 + dz2 * dz2;
        const float r3 = dx3 * dx3 + dy3 * dy3 + dz3 * dz3;
        r = fmaxf(r, fmaxf(fmaxf(r0, r1), fmaxf(r2, r3)));
    }
    for (int n = 4 * N4 + blockIdx.x * blockDim.x + threadIdx.x; n < N;
         n += gridDim.x * blockDim.x) {
        const float dx = cb[n] - mx;
        const float dy = cb[N + n] - my;
        const float dz = cb[2 * N + n] - mz;
        r = fmaxf(r, dx * dx + dy * dy + dz * dz);
    }
    for (int off = 32; off > 0; off >>= 1) r = fmaxf(r, __shfl_down(r, off));
    __shared__ float red[4];
    const int lane = threadIdx.x & 63;
    const int wv   = threadIdx.x >> 6;
    if (lane == 0) red[wv] = r;
    __syncthreads();
    if (threadIdx.x == 0) {
        const int nw = blockDim.x >> 6;
        float t = 0.f;
        for (int w = 0; w < nw; ++w) t = fmaxf(t, red[w]);
        maxp[b * PB + blockIdx.x] = sqrtf(t);  // sqrt monotone: sqrt(max r^2) == max radius
    }
}

// ---- K3: norm coords + packed (voxel idx << 17 | rank); 4 points/thread ----
__global__ void k_points(const float* __restrict__ coords, const float* __restrict__ part,
                         const float* __restrict__ maxp,
                         float* __restrict__ norm_out, unsigned int* __restrict__ pk,
                         int* __restrict__ counts, int N) {
    const int b = blockIdx.y;
    __shared__ float sp[PB * 3];
    __shared__ float mp[PB];
    for (int x = threadIdx.x; x < PB * 3; x += blockDim.x) sp[x] = part[b * PB * 3 + x];
    for (int x = threadIdx.x; x < PB; x += blockDim.x) mp[x] = maxp[b * PB + x];
    __syncthreads();
    const float invN = 1.0f / (float)N;
    float mean[3] = {0.f, 0.f, 0.f};
    float mrad = 0.f;
    for (int x = 0; x < PB; ++x) {
        mean[0] += sp[x * 3]; mean[1] += sp[x * 3 + 1]; mean[2] += sp[x * 3 + 2];
        mrad = fmaxf(mrad, mp[x]);
    }
    const float scale = 2.0f * mrad;
    const float m0 = mean[0] * invN, m1 = mean[1] * invN, m2 = mean[2] * invN;

    const int i = blockIdx.x * blockDim.x + threadIdx.x;  // float4 index
    const int n0 = i * 4;
    if (n0 >= N) return;
    const float* cb = coords + (size_t)b * 3 * N;
    float* nb = norm_out + (size_t)b * 3 * N;
    int* cnts = counts + b * R3V;

    if (n0 + 4 <= N) {
        float4 cx = ((const float4*)cb)[i];
        float4 cy = ((const float4*)(cb + N))[i];
        float4 cz = ((const float4*)(cb + 2 * N))[i];
        float nx[4] = {cx.x, cx.y, cx.z, cx.w};
        float ny[4] = {cy.x, cy.y, cy.z, cy.w};
        float nz[4] = {cz.x, cz.y, cz.z, cz.w};
        int flat[4];
#pragma unroll
        for (int k = 0; k < 4; ++k) {
            float a = fminf(fmaxf(((nx[k] - m0) / scale + 0.5f) * (float)RESV, 0.0f), (float)(RESV - 1));
            float bq = fminf(fmaxf(((ny[k] - m1) / scale + 0.5f) * (float)RESV, 0.0f), (float)(RESV - 1));
            float c = fminf(fmaxf(((nz[k] - m2) / scale + 0.5f) * (float)RESV, 0.0f), (float)(RESV - 1));
            nx[k] = a; ny[k] = bq; nz[k] = c;
            flat[k] = ((int)rintf(a) * RESV + (int)rintf(bq)) * RESV + (int)rintf(c);
        }
        ((float4*)(nb))[i]         = make_float4(nx[0], nx[1], nx[2], nx[3]);
        ((float4*)(nb + N))[i]     = make_float4(ny[0], ny[1], ny[2], ny[3]);
        ((float4*)(nb + 2 * N))[i] = make_float4(nz[0], nz[1], nz[2], nz[3]);
        uint4 o;
        o.x = ((unsigned int)flat[0] << 17) | (unsigned int)atomicAdd(&cnts[flat[0]], 1);
        o.y = ((unsigned int)flat[1] << 17) | (unsigned int)atomicAdd(&cnts[flat[1]], 1);
        o.z = ((unsigned int)flat[2] << 17) | (unsigned int)atomicAdd(&cnts[flat[2]], 1);
        o.w = ((unsigned int)flat[3] << 17) | (unsigned int)atomicAdd(&cnts[flat[3]], 1);
        ((uint4*)(pk + (size_t)b * N))[i] = o;
    } else {
        for (int n = n0; n < N; ++n) {
            int flat = 0;
            float v[3] = {cb[n], cb[N + n], cb[2 * N + n]};
            float m[3] = {m0, m1, m2};
#pragma unroll
            for (int d = 0; d < 3; ++d) {
                float nc = fminf(fmaxf(((v[d] - m[d]) / scale + 0.5f) * (float)RESV, 0.0f),
                                 (float)(RESV - 1));
                nb[d * N + n] = nc;
                flat = flat * RESV + (int)rintf(nc);
            }
            const int jl = atomicAdd(&cnts[flat], 1);
            pk[(size_t)b * N + n] = ((unsigned int)flat << 17) | (unsigned int)jl;
        }
    }
}

// ---- K4: per-batch exclusive scan of counts -> start (stride R3P1, sentinel) ----
__global__ __launch_bounds__(1024, 1) void k_scan(const int* __restrict__ counts,
                                                  int* __restrict__ start, int N) {
    const int b = blockIdx.x;
    const int t = threadIdx.x;
    const int base  = b * R3V + t * 32;
    const int baseS = b * R3P1 + t * 32;
    int c[32];
    int T = 0;
#pragma unroll
    for (int i = 0; i < 32; ++i) { c[i] = counts[base + i]; T += c[i]; }
    int incl = T;
    const int lane = t & 63;
    for (int off = 1; off < 64; off <<= 1) {
        int y = __shfl_up(incl, off);
        if (lane >= off) incl += y;
    }
    __shared__ int wsum[16];
    __shared__ int wbase[16];
    const int w = t >> 6;
    if (lane == 63) wsum[w] = incl;
    __syncthreads();
    if (t == 0) {
        int run = 0;
        for (int i = 0; i < 16; ++i) { wbase[i] = run; run += wsum[i]; }
    }
    __syncthreads();
    int run = wbase[w] + incl - T;  // exclusive prefix
#pragma unroll
    for (int i = 0; i < 32; ++i) {
        start[baseS + i] = run;
        run += c[i];
    }
    if (t == 1023) start[b * R3P1 + R3V] = run;  // == N
}

// ---- K5: feats [B,64,N] fp32 -> fTs [B,N,64] bf16, rows in sorted order ----
__global__ __launch_bounds__(1024, 2) void k_transpose_perm(
        const float* __restrict__ feats, const unsigned int* __restrict__ pk,
        const int* __restrict__ startv,
        unsigned int* __restrict__ fTs32, int* __restrict__ voxid, int N) {
    __shared__ unsigned short tile[256][66];
    __shared__ int jrow[256];
    const int b  = blockIdx.y;
    const int n0 = blockIdx.x * 256;
    const int t  = threadIdx.x;
    const float* fb = feats + (size_t)b * 64 * N;

    const int c = t >> 4;
    const int q = t & 15;
    if (n0 + 256 <= N) {
#pragma unroll
        for (int i = 0; i < 4; ++i) {
            const int nn = q * 4 + i * 64;
            const float4 f = *(const float4*)(fb + (size_t)c * N + n0 + nn);
            tile[nn + 0][c] = f2bf(f.x);
            tile[nn + 1][c] = f2bf(f.y);
            tile[nn + 2][c] = f2bf(f.z);
            tile[nn + 3][c] = f2bf(f.w);
        }
    } else {
        for (int i = 0; i < 4; ++i) {
            const int nn = q * 4 + i * 64;
            for (int u = 0; u < 4; ++u) {
                const int n = n0 + nn + u;
                tile[nn + u][c] = f2bf((n < N) ? fb[(size_t)c * N + n] : 0.f);
            }
        }
    }
    if (t < 256) {
        const int n = n0 + t;
        if (n < N) {
            const unsigned int p = pk[(size_t)b * N + n];
            const int v = (int)(p >> 17);
            const int j = startv[(size_t)b * R3P1 + v] + (int)(p & 0x1FFFFu);
            jrow[t] = j;
            voxid[(size_t)b * N + j] = v;
        }
    }
    __syncthreads();

    // permuted store: 4 passes, 4 rows per wave instruction, 8B/lane
    const int wv   = t >> 6;
    const int lane = t & 63;
    const int lc   = lane & 15;     // channel quad
    const int pr   = lane >> 4;     // row within 4-row group
    uint2* fo2 = (uint2*)fTs32 + (size_t)b * N * 16;
#pragma unroll
    for (int k = 0; k < 4; ++k) {
        const int p = k * 64 + wv * 4 + pr;
        if (n0 + p < N) {
            const uint2 d = *(const uint2*)&tile[p][4 * lc];
            fo2[(size_t)jrow[p] * 16 + lc] = d;
        }
    }
}

// ---- K6: atomic-free segmented reduction over sorted rows (2D grid) ----
__global__ __launch_bounds__(256) void k_gather4(const unsigned int* __restrict__ fTs32,
                                                 const int* __restrict__ voxid,
                                                 const int* __restrict__ startv,
                                                 unsigned int* __restrict__ gridT2,
                                                 int N, int nchunk) {
    const int w     = threadIdx.x >> 6;
    const int lane  = threadIdx.x & 63;
    const int p     = lane >> 4;   // row parity 0..3
    const int lc    = lane & 15;   // channel quad
    const int chunk = blockIdx.x * 4 + w;
    if (chunk >= nchunk) return;
    const int b    = blockIdx.y;
    const int c0   = chunk * CH;
    const int end0 = min(c0 + CH, N);
    const uint2* fb = (const uint2*)(fTs32 + (size_t)b * N * 32);
    const int* vi = voxid  + (size_t)b * N;
    const int* sv = startv + (size_t)b * R3P1;
    uint2* gT = (uint2*)(gridT2) + (size_t)b * R3V * 16;

    int j;
    {
        const int v = vi[c0];
        const int s = sv[v];
        j = (s < c0) ? sv[v + 1] : s;
    }
    while (j < end0) {
        const int v = vi[j];           // wave-uniform
        const int e = sv[v + 1];
        float a0 = 0.f, a1 = 0.f, a2 = 0.f, a3 = 0.f;
        int r = j + p;
        for (; r + 12 < e; r += 16) {  // 4 uint2 loads in flight per lane
            const uint2 u0 = fb[(size_t)(r + 0) * 16 + lc];
            const uint2 u1 = fb[(size_t)(r + 4) * 16 + lc];
            const uint2 u2 = fb[(size_t)(r + 8) * 16 + lc];
            const uint2 u3 = fb[(size_t)(r + 12) * 16 + lc];
            a0 += (blo(u0.x) + blo(u1.x)) + (blo(u2.x) + blo(u3.x));
            a1 += (bhi(u0.x) + bhi(u1.x)) + (bhi(u2.x) + bhi(u3.x));
            a2 += (blo(u0.y) + blo(u1.y)) + (blo(u2.y) + blo(u3.y));
            a3 += (bhi(u0.y) + bhi(u1.y)) + (bhi(u2.y) + bhi(u3.y));
        }
        for (; r < e; r += 4) {
            const uint2 u = fb[(size_t)r * 16 + lc];
            a0 += blo(u.x);
            a1 += bhi(u.x);
            a2 += blo(u.y);
            a3 += bhi(u.y);
        }
        a0 += __shfl_xor(a0, 16); a0 += __shfl_xor(a0, 32);
        a1 += __shfl_xor(a1, 16); a1 += __shfl_xor(a1, 32);
        a2 += __shfl_xor(a2, 16); a2 += __shfl_xor(a2, 32);
        a3 += __shfl_xor(a3, 16); a3 += __shfl_xor(a3, 32);
        if (p == 0) {
            gT[(size_t)v * 16 + lc] = make_uint2(pkbf(a0, a1), pkbf(a2, a3));
        }
        j = e;
    }
}

// ---- K7: gridT bf16 [B,R3,64] -> grid fp32 [B,64,R3], /cnt, cnt==0 -> 0 ----
__global__ __launch_bounds__(256) void k_fin(const unsigned int* __restrict__ gridT2,
                                             const int* __restrict__ counts,
                                             float* __restrict__ grid) {
    __shared__ float tile[64][65];
    const int b    = blockIdx.y;
    const int v0   = blockIdx.x * 64;
    const int t    = threadIdx.x;
    const int lane = t & 63;
    const int w    = t >> 6;
    const unsigned int* g = gridT2 + ((size_t)b * R3V + v0) * 32;
#pragma unroll
    for (int k = 0; k < 8; ++k) {
        const int i  = t + k * 256;  // v*32 + cd
        const int v  = i >> 5;
        const int cd = i & 31;
        const unsigned int u = g[i];
        tile[v][2 * cd]     = blo(u);
        tile[v][2 * cd + 1] = bhi(u);
    }
    __syncthreads();
    const int cnt  = counts[(size_t)b * R3V + v0 + lane];
    const float rc = 1.0f / fmaxf((float)cnt, 1.0f);
    const bool occ = cnt > 0;
    float* gb = grid + (size_t)b * 64 * R3V;
#pragma unroll
    for (int k = 0; k < 16; ++k) {
        const int c = w + k * 4;
        gb[(size_t)c * R3V + v0 + lane] = occ ? tile[lane][c] * rc : 0.0f;
    }
}

// ============================ fallback: LDS-atomic scatter ============================

__device__ __forceinline__ int swz(int v) {
    return v ^ ((v >> 5) & 31) ^ ((v >> 10) & 31);
}

__global__ void k_recip_fb(const int* __restrict__ cnt, float* __restrict__ recip, int total) {
    const int i = blockIdx.x * blockDim.x + threadIdx.x;
    if (i < total) recip[i] = 1.0f / fmaxf((float)cnt[i], 1.0f);
}

__global__ __launch_bounds__(1024, 1) void k_scatter_lds(
        const float* __restrict__ feats, const unsigned int* __restrict__ pk,
        const float* __restrict__ recip, float* __restrict__ grid, int N, int C) {
    extern __shared__ float acc[];
    const int bc  = blockIdx.x;
    const int b   = bc / C;
    const int tid = threadIdx.x;
    for (int i = tid * 4; i < R3V; i += blockDim.x * 4)
        *(float4*)(acc + i) = make_float4(0.f, 0.f, 0.f, 0.f);
    __syncthreads();
    const float* fb = feats + (size_t)bc * N;
    const unsigned int* ib = pk + (size_t)b * N;
    for (int n = tid; n < N; n += blockDim.x) atomicAdd(&acc[swz((int)(ib[n] >> 17))], fb[n]);
    __syncthreads();
    const float* rb = recip + (size_t)b * R3V;
    float*       gb = grid  + (size_t)bc * R3V;
    for (int i = tid; i < R3V; i += blockDim.x)
        gb[i] = acc[swz(i)] * rb[i];
}

// ============================ launch ============================

extern "C" void kernel_launch(void* const* d_in, const int* in_sizes, int n_in,
                              void* d_out, int out_size, void* d_ws, size_t ws_size,
                              hipStream_t stream) {
    const float* feats  = (const float*)d_in[0];
    const float* coords = (const float*)d_in[1];

    const long long s0 = in_sizes[0], s1 = in_sizes[1];
    const int BC = (int)(((long long)out_size - s1) / R3V);  // B*C
    const int N  = (int)(s0 / BC);
    const int B  = (int)(s1 / (3LL * N));
    const int C  = BC / B;

    float* out_grid = (float*)d_out;               // [B, C, R3]
    float* out_norm = out_grid + (size_t)BC * R3V; // [B, 3, N]

    // ws layout (float32 slots). Header = 4096 floats (PB=128 partials).
    const size_t BR3 = (size_t)B * R3V;
    const size_t BN  = (size_t)B * N;
    const size_t o_counts = 4096;
    const size_t o_start  = o_counts + BR3;
    const size_t o_recip  = o_start + (size_t)B * R3P1;  // fallback only
    const size_t o_pk     = o_recip + BR3;
    const size_t o_voxid  = o_pk + BN;
    size_t o_gridT = (o_voxid + BN + 63) & ~(size_t)63;        // bf16: BR3*32 slots
    size_t o_fTs   = (o_gridT + BR3 * 32 + 63) & ~(size_t)63;  // bf16: BN*32 slots
    const size_t need = (o_fTs + BN * 32) * sizeof(float);

    float*        ws_part = (float*)d_ws;                  // [B*PB*3]
    float*        ws_maxp = (float*)d_ws + 3072;           // [B*PB]
    int*          counts  = (int*)d_ws + o_counts;
    int*          startv  = (int*)d_ws + o_start;
    float*        recip   = (float*)d_ws + o_recip;
    unsigned int* pk      = (unsigned int*)d_ws + o_pk;
    int*          voxid   = (int*)d_ws + o_voxid;
    unsigned int* gridT2  = (unsigned int*)((float*)d_ws + o_gridT);
    unsigned int* fTs32   = (unsigned int*)((float*)d_ws + o_fTs);

    const int BLK = 256;
    const int nInt4 = (int)(BR3 / 4);
    dim3 gRed(PB, B);
    // k_sums also zeroes counts (guarded; PB*B*256 threads >= BR3/4)
    k_sums<<<gRed, BLK, 0, stream>>>(coords, ws_part, (int4*)counts, nInt4, N);
    k_maxrad<<<gRed, BLK, 0, stream>>>(coords, ws_part, ws_maxp, N);

    const int nQuads = (N + 3) / 4;
    dim3 gPts((nQuads + BLK - 1) / BLK, B);
    k_points<<<gPts, BLK, 0, stream>>>(coords, ws_part, ws_maxp, out_norm, pk, counts, N);

    if (ws_size >= need && C == 64) {
        k_scan<<<dim3(B), 1024, 0, stream>>>(counts, startv, N);
        dim3 gT((N + 255) / 256, B);
        k_transpose_perm<<<gT, 1024, 0, stream>>>(feats, pk, startv, fTs32, voxid, N);
        const int nchunk = (N + CH - 1) / CH;
        dim3 gG((nchunk + 3) / 4, B);
        k_gather4<<<gG, 256, 0, stream>>>(fTs32, voxid, startv, gridT2, N, nchunk);
        dim3 gF(R3V / 64, B);
        k_fin<<<gF, 256, 0, stream>>>(gridT2, counts, out_grid);
    } else {
        const int tot = B * R3V;
        k_recip_fb<<<(tot + BLK - 1) / BLK, BLK, 0, stream>>>(counts, recip, tot);
        k_scatter_lds<<<dim3(BC), 1024, R3V * sizeof(float), stream>>>(
            feats, pk, recip, out_grid, N, C);
    }
}